// Round 4
// baseline (267.158 us; speedup 1.0000x reference)
//
#include <hip/hip_runtime.h>

#define NPTS 4096
#define CDIM 256
#define C4DIM 64

typedef __bf16 bf16x8 __attribute__((ext_vector_type(8)));
typedef float  f32x4  __attribute__((ext_vector_type(4)));

__device__ __forceinline__ void async_cp16(const void* g, void* l) {
    __builtin_amdgcn_global_load_lds(
        (const __attribute__((address_space(1))) void*)g,
        (__attribute__((address_space(3))) void*)l, 16, 0, 0);
}

// ---------------------------------------------------------------------------
// W prep: fp32 -> bf16, rows [Wq(64) | Wk(64) | Wv(256)] = 384 x 256,
// with 16B-group swizzle within each 512B row: phys_group = g ^ (row & 7).
// (verbatim, HW-verified)
// ---------------------------------------------------------------------------
__global__ __launch_bounds__(256) void wprep_kernel(
    const float* __restrict__ Wq, const float* __restrict__ Wk,
    const float* __restrict__ Wv, __bf16* __restrict__ wsz)
{
    int idx = blockIdx.x * 256 + threadIdx.x;   // 0..24575
    int row = idx >> 6;                         // 0..383
    int l   = idx & 63;                         // float4 index within row
    const float* src;
    if (row < 64)       src = Wq + (size_t)row * CDIM;
    else if (row < 128) src = Wk + (size_t)(row - 64) * CDIM;
    else                src = Wv + (size_t)(row - 128) * CDIM;
    float4 f = *(const float4*)&src[l * 4];
    int g  = l >> 1;                 // logical 16B group 0..31
    int gp = g ^ (row & 7);          // physical slot
    union { __bf16 h[4]; uint2 u; } pk;
    pk.h[0] = (__bf16)f.x; pk.h[1] = (__bf16)f.y;
    pk.h[2] = (__bf16)f.z; pk.h[3] = (__bf16)f.w;
    *(uint2*)&wsz[(size_t)row * CDIM + gp * 8 + (l & 1) * 4] = pk.u;
}

// ---------------------------------------------------------------------------
// MFMA projection (round-7 version, verified -4.6us vs r6): 32-n tiles,
// grid (NPTS/32, B), block 256; LDS 64KB -> 2 blocks/CU.
// ---------------------------------------------------------------------------
__global__ __launch_bounds__(256, 2) void proj_kernel(
    const float* __restrict__ x,
    const float* __restrict__ bq, const float* __restrict__ bk,
    const float* __restrict__ bv, const __bf16* __restrict__ wsz,
    __bf16* __restrict__ qT, __bf16* __restrict__ kT, __bf16* __restrict__ vo)
{
    __shared__ __align__(16) unsigned char sm[65536];
    auto Xs = (float (*)[33])sm;                 // [256][33] fp32, dies after A-build

    const int t    = threadIdx.x;
    const int w    = t >> 6;
    const int lane = t & 63;
    const int quad = lane >> 4;
    const int l16  = lane & 15;
    const int nq   = w >> 1;
    const int th   = w & 1;

    const int n0 = blockIdx.x * 32;
    const int b  = blockIdx.y;

    #pragma unroll
    for (int s = 0; s < 8; s++) {
        int lin = t + 256 * s;
        int c = lin >> 3, n4 = (lin & 7) * 4;
        *(float4*)&Xs[c][n4] =
            *(const float4*)&x[((size_t)b * CDIM + c) * NPTS + n0 + n4];
    }
    __syncthreads();

    bf16x8 af[8];
    #pragma unroll
    for (int kc = 0; kc < 8; kc++) {
        union { __bf16 h8[8]; bf16x8 v; } pk;
        #pragma unroll
        for (int u = 0; u < 8; u++)
            pk.h8[u] = (__bf16)Xs[kc * 32 + quad * 8 + u][16 * nq + l16];
        af[kc] = pk.v;
    }
    __syncthreads();

    const int lhalf = lane >> 5;
    const int rlow  = (2 * w + lhalf) & 7;
    const int slane = ((lane & 31) ^ rlow) * 8;

    #pragma unroll
    for (int s = 0; s < 8; s++)
        async_cp16(wsz + (size_t)(8 * s + 2 * w + lhalf) * CDIM + slane,
                   sm + (s * 4 + w) * 1024);

    f32x4 acc[6][2];
    #pragma unroll
    for (int ot = 0; ot < 6; ot++) {
        acc[ot][0] = (f32x4)(0.f);
        acc[ot][1] = (f32x4)(0.f);
    }

    #pragma unroll
    for (int ot = 0; ot < 6; ot++) {
        __syncthreads();
        if (ot < 5) {
            #pragma unroll
            for (int s = 0; s < 8; s++)
                async_cp16(wsz + (size_t)((ot + 1) * 64 + 8 * s + 2 * w + lhalf) * CDIM + slane,
                           sm + ((ot + 1) & 1) * 32768 + (s * 4 + w) * 1024);
        }
        const unsigned char* Wp = sm + (ot & 1) * 32768;
        #pragma unroll
        for (int kc = 0; kc < 8; kc++) {
            bf16x8 bw[2];
            #pragma unroll
            for (int tcl = 0; tcl < 2; tcl++)
                bw[tcl] = *(const bf16x8*)(Wp + (16 * (2 * th + tcl) + l16) * 512
                                              + (((kc * 4 + quad) ^ (l16 & 7)) << 4));
            #pragma unroll
            for (int tcl = 0; tcl < 2; tcl++)
                acc[ot][tcl] = __builtin_amdgcn_mfma_f32_16x16x32_bf16(
                    af[kc], bw[tcl], acc[ot][tcl], 0, 0, 0);
        }
    }

    {
        auto OT = (float (*)[68])sm;
        #pragma unroll
        for (int ot = 0; ot < 2; ot++) {
            __syncthreads();
            const float* bias = ot ? bk : bq;
            #pragma unroll
            for (int tcl = 0; tcl < 2; tcl++) {
                float bs = bias[16 * (2 * th + tcl) + l16];
                #pragma unroll
                for (int r4 = 0; r4 < 4; r4++)
                    OT[16 * nq + 4 * quad + r4][16 * (2 * th + tcl) + l16] =
                        acc[ot][tcl][r4] + bs;
            }
            __syncthreads();
            __bf16* outp = (ot == 0 ? qT : kT) + (size_t)b * NPTS * C4DIM;
            int n = t >> 3, op = (t & 7) * 8;
            f32x4 o0 = *(const f32x4*)&OT[n][op];
            f32x4 o1 = *(const f32x4*)&OT[n][op + 4];
            union { __bf16 h[8]; uint4 u; } pk;
            #pragma unroll
            for (int u2 = 0; u2 < 4; u2++) {
                pk.h[u2]     = (__bf16)o0[u2];
                pk.h[u2 + 4] = (__bf16)o1[u2];
            }
            *(uint4*)&outp[(size_t)(n0 + n) * C4DIM + op] = pk.u;
        }
    }
    {
        auto OTv = (float (*)[36])sm;
        #pragma unroll
        for (int ot = 2; ot < 6; ot++) {
            __syncthreads();
            #pragma unroll
            for (int tcl = 0; tcl < 2; tcl++) {
                float bs = bv[(ot - 2) * 64 + 16 * (2 * th + tcl) + l16];
                f32x4 v4 = acc[ot][tcl];
                v4[0] += bs; v4[1] += bs; v4[2] += bs; v4[3] += bs;
                *(f32x4*)&OTv[16 * (2 * th + tcl) + l16][16 * nq + 4 * quad] = v4;
            }
            __syncthreads();
            int cl = t >> 2, np = (t & 3) * 8;
            int ch = (ot - 2) * 64 + cl;
            f32x4 o0 = *(const f32x4*)&OTv[cl][np];
            f32x4 o1 = *(const f32x4*)&OTv[cl][np + 4];
            union { __bf16 h[8]; uint4 u; } pk;
            #pragma unroll
            for (int u2 = 0; u2 < 4; u2++) {
                pk.h[u2]     = (__bf16)o0[u2];
                pk.h[u2 + 4] = (__bf16)o1[u2];
            }
            *(uint4*)&vo[((size_t)b * CDIM + ch) * NPTS + n0 + np] = pk.u;
        }
    }
}

// ---------------------------------------------------------------------------
// MFMA flash attention, round 10: barrier-free main loop.
// grid (NPTS/64, CDIM/128, B) = 512 blocks, block 256.
// K and V B-frags loaded straight from global (both L2-resident and stored
// in B-frag-contiguous layouts: kT [j][64c], vo [c][4096j]) into ping-pong
// registers prefetched one j-tile ahead. No LDS staging, no DMA, and since
// the Ps write->read is same-wave-only, the 64-iter j-loop has ZERO
// __syncthreads: waves slip freely (kills the per-iter vmcnt(0)+barrier
// drain and ~60% of LDS pipe traffic, the two dominant costs in r9).
// K-from-global pattern correctness-verified in r8; V is the same pattern.
// exp2-fma + setprio micros kept (verified r9).
// ---------------------------------------------------------------------------
__global__ __launch_bounds__(256, 2) void attn_kernel(
    const __bf16* __restrict__ qT, const __bf16* __restrict__ kT,
    const __bf16* __restrict__ vin, const float* __restrict__ xin,
    const float* __restrict__ gptr, float* __restrict__ out)
{
    __shared__ __align__(16) unsigned char sm[35072];
    auto Ps  = (__bf16 (*)[72])sm;           // [64][72] bf16 (144B rows) = 9216
    // epilogue overlays (after barrier): Opart 128x272B = 34816, Lp at 34816,
    // OTa [128][68] fp32 = 34816

    const int t    = threadIdx.x;
    const int w    = t >> 6;
    const int lane = t & 63;
    const int quad = lane >> 4;
    const int l16  = lane & 15;
    const int r    = w >> 1;    // i row half
    const int jh   = w & 1;     // j half

    const int b  = blockIdx.z;
    const int i0 = blockIdx.x * 64;
    const int c0 = blockIdx.y * 128;

    const __bf16* qb = qT  + (size_t)b * NPTS * C4DIM;
    const __bf16* kb = kT  + (size_t)b * NPTS * C4DIM;
    const __bf16* vb = vin + (size_t)b * CDIM * NPTS;

    // Q A-frags: rows i0 + 32r + 16rt + l16, k = kc*32 + quad*8
    bf16x8 aq[2][2];
    #pragma unroll
    for (int rt = 0; rt < 2; rt++)
        #pragma unroll
        for (int kc = 0; kc < 2; kc++)
            aq[rt][kc] = *(const bf16x8*)&qb[(size_t)(i0 + 32 * r + 16 * rt + l16) * C4DIM
                                             + kc * 32 + quad * 8];

    bf16x8 vone;
    #pragma unroll
    for (int u = 0; u < 8; u++) vone[u] = (__bf16)1.0f;

    f32x4 O[2][8], lacc[2];
    #pragma unroll
    for (int rt = 0; rt < 2; rt++) {
        lacc[rt] = (f32x4)(0.f);
        #pragma unroll
        for (int tc = 0; tc < 8; tc++) O[rt][tc] = (f32x4)(0.f);
    }

    // K B-frag loader: n = j = 32jh + 16ct + l16, k = c = kc*32 + quad*8 (+u)
    auto kload = [&](bf16x8 (&dst)[2][2], int j) {
        #pragma unroll
        for (int kc = 0; kc < 2; kc++)
            #pragma unroll
            for (int ct = 0; ct < 2; ct++)
                dst[kc][ct] = *(const bf16x8*)&kb[(size_t)(j + 32 * jh + 16 * ct + l16) * C4DIM
                                                  + kc * 32 + quad * 8];
    };
    // V B-frag loader: n = c = 16tc + l16, k = j = 32jh + quad*8 (+u)
    auto vload = [&](bf16x8 (&dst)[8], int j) {
        #pragma unroll
        for (int tc = 0; tc < 8; tc++)
            dst[tc] = *(const bf16x8*)&vb[(size_t)(c0 + 16 * tc + l16) * NPTS
                                          + j + 32 * jh + quad * 8];
    };

    // prologue: tile-0 frags
    bf16x8 kr0[2][2], kr1[2][2], vr0[8], vr1[8];
    kload(kr0, 0);
    vload(vr0, 0);

    auto body = [&](int j0, bf16x8 (&kcur)[2][2], bf16x8 (&knext)[2][2],
                    bf16x8 (&vcur)[8], bf16x8 (&vnext)[8]) {
        // prefetch next j-tile (wrap-clamped dummy on last iter)
        const int jk = (j0 + 64) & (NPTS - 1);
        kload(knext, jk);
        vload(vnext, jk);

        // ---- QK: S[rt][ct] = 32 i x 32 j (slice jh)
        f32x4 S[2][2];
        #pragma unroll
        for (int rt = 0; rt < 2; rt++)
            #pragma unroll
            for (int ct = 0; ct < 2; ct++) S[rt][ct] = (f32x4)(0.f);
        #pragma unroll
        for (int kc = 0; kc < 2; kc++)
            #pragma unroll
            for (int rt = 0; rt < 2; rt++)
                #pragma unroll
                for (int ct = 0; ct < 2; ct++)
                    S[rt][ct] = __builtin_amdgcn_mfma_f32_16x16x32_bf16(
                        aq[rt][kc], kcur[kc][ct], S[rt][ct], 0, 0, 0);

        // ---- P = exp(s - 32) = exp2(fma(s, log2e, -32*log2e)); b16 scatter
        #pragma unroll
        for (int rt = 0; rt < 2; rt++)
            #pragma unroll
            for (int ct = 0; ct < 2; ct++)
                #pragma unroll
                for (int r4 = 0; r4 < 4; r4++)
                    Ps[32 * r + 16 * rt + 4 * quad + r4][32 * jh + 16 * ct + l16] =
                        (__bf16)__builtin_amdgcn_exp2f(
                            __builtin_fmaf(S[rt][ct][r4], 1.44269504088896340736f,
                                           -46.16624130844683f));

        // ---- PV over own j slice (same-wave LDS RAW: no barrier)
        bf16x8 ap[2];
        #pragma unroll
        for (int rt = 0; rt < 2; rt++)
            ap[rt] = *(const bf16x8*)((const char*)&Ps[32 * r + 16 * rt + l16][0]
                                      + jh * 64 + quad * 16);
        __builtin_amdgcn_s_setprio(1);
        #pragma unroll
        for (int tc = 0; tc < 8; tc++)
            #pragma unroll
            for (int rt = 0; rt < 2; rt++)
                O[rt][tc] = __builtin_amdgcn_mfma_f32_16x16x32_bf16(
                    ap[rt], vcur[tc], O[rt][tc], 0, 0, 0);
        #pragma unroll
        for (int rt = 0; rt < 2; rt++)
            lacc[rt] = __builtin_amdgcn_mfma_f32_16x16x32_bf16(ap[rt], vone, lacc[rt], 0, 0, 0);
        __builtin_amdgcn_s_setprio(0);
    };

    for (int jj = 0; jj < NPTS; jj += 128) {
        body(jj,      kr0, kr1, vr0, vr1);
        body(jj + 64, kr1, kr0, vr1, vr0);
    }

    // ---- epilogue: combine j-half partials, gamma/l scale, transpose, +x
    __syncthreads();   // all Ps reads done; sm reusable
    const float g = gptr[0];
    float* Lp = (float*)(sm + 34816);

    if (jh == 1) {
        float* dst = (float*)(sm + (size_t)(r * 64 + lane) * 272);
        #pragma unroll
        for (int rt = 0; rt < 2; rt++)
            #pragma unroll
            for (int tc = 0; tc < 8; tc++)
                *(f32x4*)(dst + (rt * 8 + tc) * 4) = O[rt][tc];
        if (l16 == 0) {
            #pragma unroll
            for (int rt = 0; rt < 2; rt++)
                #pragma unroll
                for (int r4 = 0; r4 < 4; r4++)
                    Lp[32 * r + 16 * rt + 4 * quad + r4] = lacc[rt][r4];
        }
    }
    __syncthreads();

    float inv[2][4];
    if (jh == 0) {
        const float* src = (const float*)(sm + (size_t)(r * 64 + lane) * 272);
        #pragma unroll
        for (int rt = 0; rt < 2; rt++)
            #pragma unroll
            for (int tc = 0; tc < 8; tc++)
                O[rt][tc] += *(const f32x4*)(src + (rt * 8 + tc) * 4);
        #pragma unroll
        for (int rt = 0; rt < 2; rt++)
            #pragma unroll
            for (int r4 = 0; r4 < 4; r4++) {
                float ls = lacc[rt][r4] + Lp[32 * r + 16 * rt + 4 * quad + r4];
                inv[rt][r4] = g / ls;
            }
    }
    __syncthreads();   // partial reads done; OTa overlays same bytes

    auto OTa = (float (*)[68])sm;            // [128][68] fp32
    if (jh == 0) {
        #pragma unroll
        for (int rt = 0; rt < 2; rt++)
            #pragma unroll
            for (int tc = 0; tc < 8; tc++) {
                int c = 16 * tc + l16;
                float4 f;
                f.x = O[rt][tc][0] * inv[rt][0];
                f.y = O[rt][tc][1] * inv[rt][1];
                f.z = O[rt][tc][2] * inv[rt][2];
                f.w = O[rt][tc][3] * inv[rt][3];
                *(float4*)&OTa[c][32 * r + 16 * rt + 4 * quad] = f;
            }
    }
    __syncthreads();

    const float* xb = xin + (size_t)b * CDIM * NPTS;
    float*       ob = out + (size_t)b * CDIM * NPTS;
    #pragma unroll
    for (int s = 0; s < 8; s++) {
        int lin = t + 256 * s;            // 0..2047
        int c = lin >> 4, col = (lin & 15) * 4;
        size_t gi = (size_t)(c0 + c) * NPTS + i0 + col;
        float4 ov = *(const float4*)&OTa[c][col];
        float4 xv = *(const float4*)&xb[gi];
        float4 rr;
        rr.x = ov.x + xv.x; rr.y = ov.y + xv.y;
        rr.z = ov.z + xv.z; rr.w = ov.w + xv.w;
        *(float4*)&ob[gi] = rr;
    }
}

extern "C" void kernel_launch(void* const* d_in, const int* in_sizes, int n_in,
                              void* d_out, int out_size, void* d_ws, size_t ws_size,
                              hipStream_t stream) {
    const float* x     = (const float*)d_in[0];
    const float* Wq    = (const float*)d_in[1];
    const float* bq    = (const float*)d_in[2];
    const float* Wk    = (const float*)d_in[3];
    const float* bk    = (const float*)d_in[4];
    const float* Wv    = (const float*)d_in[5];
    const float* bv    = (const float*)d_in[6];
    const float* gamma = (const float*)d_in[7];

    const int B = 4;
    __bf16* qT  = (__bf16*)d_ws;                        // 2 MB
    __bf16* kT  = qT + (size_t)B * NPTS * C4DIM;        // 2 MB
    __bf16* v   = kT + (size_t)B * NPTS * C4DIM;        // 8 MB
    __bf16* wsz = v  + (size_t)B * CDIM * NPTS;         // 192 KB (swizzled bf16 W)

    wprep_kernel<<<96, 256, 0, stream>>>(Wq, Wk, Wv, wsz);

    proj_kernel<<<dim3(NPTS/32, B), 256, 0, stream>>>(
        x, bq, bk, bv, wsz, qT, kT, v);

    attn_kernel<<<dim3(NPTS/64, CDIM/128, B), 256, 0, stream>>>(
        qT, kT, v, x, gamma, (float*)d_out);
}

// Round 5
// 163.277 us; speedup vs baseline: 1.6362x; 1.6362x over previous
//
#include <hip/hip_runtime.h>

#define NPTS 4096
#define CDIM 256
#define C4DIM 64

typedef __bf16 bf16x8 __attribute__((ext_vector_type(8)));
typedef float  f32x4  __attribute__((ext_vector_type(4)));

__device__ __forceinline__ void async_cp16(const void* g, void* l) {
    __builtin_amdgcn_global_load_lds(
        (const __attribute__((address_space(1))) void*)g,
        (__attribute__((address_space(3))) void*)l, 16, 0, 0);
}

// ---------------------------------------------------------------------------
// W prep: fp32 -> bf16, rows [Wq(64) | Wk(64) | Wv(256)] = 384 x 256,
// with 16B-group swizzle within each 512B row: phys_group = g ^ (row & 7).
// (verbatim, HW-verified)
// ---------------------------------------------------------------------------
__global__ __launch_bounds__(256) void wprep_kernel(
    const float* __restrict__ Wq, const float* __restrict__ Wk,
    const float* __restrict__ Wv, __bf16* __restrict__ wsz)
{
    int idx = blockIdx.x * 256 + threadIdx.x;   // 0..24575
    int row = idx >> 6;                         // 0..383
    int l   = idx & 63;                         // float4 index within row
    const float* src;
    if (row < 64)       src = Wq + (size_t)row * CDIM;
    else if (row < 128) src = Wk + (size_t)(row - 64) * CDIM;
    else                src = Wv + (size_t)(row - 128) * CDIM;
    float4 f = *(const float4*)&src[l * 4];
    int g  = l >> 1;                 // logical 16B group 0..31
    int gp = g ^ (row & 7);          // physical slot
    union { __bf16 h[4]; uint2 u; } pk;
    pk.h[0] = (__bf16)f.x; pk.h[1] = (__bf16)f.y;
    pk.h[2] = (__bf16)f.z; pk.h[3] = (__bf16)f.w;
    *(uint2*)&wsz[(size_t)row * CDIM + gp * 8 + (l & 1) * 4] = pk.u;
}

// ---------------------------------------------------------------------------
// MFMA projection (round-7 version, verified -4.6us vs r6): 32-n tiles,
// grid (NPTS/32, B), block 256; LDS 64KB -> 2 blocks/CU.
// ---------------------------------------------------------------------------
__global__ __launch_bounds__(256, 2) void proj_kernel(
    const float* __restrict__ x,
    const float* __restrict__ bq, const float* __restrict__ bk,
    const float* __restrict__ bv, const __bf16* __restrict__ wsz,
    __bf16* __restrict__ qT, __bf16* __restrict__ kT, __bf16* __restrict__ vo)
{
    __shared__ __align__(16) unsigned char sm[65536];
    auto Xs = (float (*)[33])sm;                 // [256][33] fp32, dies after A-build

    const int t    = threadIdx.x;
    const int w    = t >> 6;
    const int lane = t & 63;
    const int quad = lane >> 4;
    const int l16  = lane & 15;
    const int nq   = w >> 1;
    const int th   = w & 1;

    const int n0 = blockIdx.x * 32;
    const int b  = blockIdx.y;

    #pragma unroll
    for (int s = 0; s < 8; s++) {
        int lin = t + 256 * s;
        int c = lin >> 3, n4 = (lin & 7) * 4;
        *(float4*)&Xs[c][n4] =
            *(const float4*)&x[((size_t)b * CDIM + c) * NPTS + n0 + n4];
    }
    __syncthreads();

    bf16x8 af[8];
    #pragma unroll
    for (int kc = 0; kc < 8; kc++) {
        union { __bf16 h8[8]; bf16x8 v; } pk;
        #pragma unroll
        for (int u = 0; u < 8; u++)
            pk.h8[u] = (__bf16)Xs[kc * 32 + quad * 8 + u][16 * nq + l16];
        af[kc] = pk.v;
    }
    __syncthreads();

    const int lhalf = lane >> 5;
    const int rlow  = (2 * w + lhalf) & 7;
    const int slane = ((lane & 31) ^ rlow) * 8;

    #pragma unroll
    for (int s = 0; s < 8; s++)
        async_cp16(wsz + (size_t)(8 * s + 2 * w + lhalf) * CDIM + slane,
                   sm + (s * 4 + w) * 1024);

    f32x4 acc[6][2];
    #pragma unroll
    for (int ot = 0; ot < 6; ot++) {
        acc[ot][0] = (f32x4)(0.f);
        acc[ot][1] = (f32x4)(0.f);
    }

    #pragma unroll
    for (int ot = 0; ot < 6; ot++) {
        __syncthreads();
        if (ot < 5) {
            #pragma unroll
            for (int s = 0; s < 8; s++)
                async_cp16(wsz + (size_t)((ot + 1) * 64 + 8 * s + 2 * w + lhalf) * CDIM + slane,
                           sm + ((ot + 1) & 1) * 32768 + (s * 4 + w) * 1024);
        }
        const unsigned char* Wp = sm + (ot & 1) * 32768;
        #pragma unroll
        for (int kc = 0; kc < 8; kc++) {
            bf16x8 bw[2];
            #pragma unroll
            for (int tcl = 0; tcl < 2; tcl++)
                bw[tcl] = *(const bf16x8*)(Wp + (16 * (2 * th + tcl) + l16) * 512
                                              + (((kc * 4 + quad) ^ (l16 & 7)) << 4));
            #pragma unroll
            for (int tcl = 0; tcl < 2; tcl++)
                acc[ot][tcl] = __builtin_amdgcn_mfma_f32_16x16x32_bf16(
                    af[kc], bw[tcl], acc[ot][tcl], 0, 0, 0);
        }
    }

    {
        auto OT = (float (*)[68])sm;
        #pragma unroll
        for (int ot = 0; ot < 2; ot++) {
            __syncthreads();
            const float* bias = ot ? bk : bq;
            #pragma unroll
            for (int tcl = 0; tcl < 2; tcl++) {
                float bs = bias[16 * (2 * th + tcl) + l16];
                #pragma unroll
                for (int r4 = 0; r4 < 4; r4++)
                    OT[16 * nq + 4 * quad + r4][16 * (2 * th + tcl) + l16] =
                        acc[ot][tcl][r4] + bs;
            }
            __syncthreads();
            __bf16* outp = (ot == 0 ? qT : kT) + (size_t)b * NPTS * C4DIM;
            int n = t >> 3, op = (t & 7) * 8;
            f32x4 o0 = *(const f32x4*)&OT[n][op];
            f32x4 o1 = *(const f32x4*)&OT[n][op + 4];
            union { __bf16 h[8]; uint4 u; } pk;
            #pragma unroll
            for (int u2 = 0; u2 < 4; u2++) {
                pk.h[u2]     = (__bf16)o0[u2];
                pk.h[u2 + 4] = (__bf16)o1[u2];
            }
            *(uint4*)&outp[(size_t)(n0 + n) * C4DIM + op] = pk.u;
        }
    }
    {
        auto OTv = (float (*)[36])sm;
        #pragma unroll
        for (int ot = 2; ot < 6; ot++) {
            __syncthreads();
            #pragma unroll
            for (int tcl = 0; tcl < 2; tcl++) {
                float bs = bv[(ot - 2) * 64 + 16 * (2 * th + tcl) + l16];
                f32x4 v4 = acc[ot][tcl];
                v4[0] += bs; v4[1] += bs; v4[2] += bs; v4[3] += bs;
                *(f32x4*)&OTv[16 * (2 * th + tcl) + l16][16 * nq + 4 * quad] = v4;
            }
            __syncthreads();
            int cl = t >> 2, np = (t & 3) * 8;
            int ch = (ot - 2) * 64 + cl;
            f32x4 o0 = *(const f32x4*)&OTv[cl][np];
            f32x4 o1 = *(const f32x4*)&OTv[cl][np + 4];
            union { __bf16 h[8]; uint4 u; } pk;
            #pragma unroll
            for (int u2 = 0; u2 < 4; u2++) {
                pk.h[u2]     = (__bf16)o0[u2];
                pk.h[u2 + 4] = (__bf16)o1[u2];
            }
            *(uint4*)&vo[((size_t)b * CDIM + ch) * NPTS + n0 + np] = pk.u;
        }
    }
}

// ---------------------------------------------------------------------------
// MFMA flash attention, round 11 = r9 structure (89.5us verified: DMA-staged
// K/V double-buffer, b16 P-scatter, 64 barriers) + deferred-PV pipeline:
// PV for tile t-1 runs at the TOP of iter t using an ap register pair
// prefetched at the end of iter t-1. Post-barrier the iter issues all 12
// LDS reads (4 K-frags + 8 V-frags) then streams 26 MFMAs, the first 18 of
// which (PV+lacc) have no LDS dependency -> K-read latency hidden. The
// pre-barrier tail loses the P-read-wait->PV segment.
// Buffer safety: PV(t-1) reads V[(t-1)&1] BEFORE the barrier preceding
// DMA(t+1) into that slot; Ps rectangle is wave-private (rows [32r,+32) x
// cols [32jh,+32)), LDS ops in-order per wave -> cross-iter WAR is safe.
// exp2-fma + setprio micros kept (verified r9).
// ---------------------------------------------------------------------------
__global__ __launch_bounds__(256, 2) void attn_kernel(
    const __bf16* __restrict__ qT, const __bf16* __restrict__ kT,
    const __bf16* __restrict__ vin, const float* __restrict__ xin,
    const float* __restrict__ gptr, float* __restrict__ out)
{
    __shared__ __align__(16) unsigned char sm[58368];
    unsigned char* Kb = sm;                  // [2][64 rows][128 B]
    unsigned char* Vb = sm + 16384;          // [2][128 rows][128 B]
    auto Ps  = (__bf16 (*)[72])(sm + 49152); // [64][72] bf16 (144B rows, 16B-aligned)
    auto OTa = (float (*)[68])sm;            // [128][68] fp32, epilogue overlay
    float* Lp = (float*)(sm + 34816);        // [64] l-partials (after Opart extent)

    const int t    = threadIdx.x;
    const int w    = t >> 6;
    const int lane = t & 63;
    const int quad = lane >> 4;
    const int l16  = lane & 15;
    const int r    = w >> 1;    // row half
    const int jh   = w & 1;     // j half

    const int b  = blockIdx.z;
    const int i0 = blockIdx.x * 64;
    const int c0 = blockIdx.y * 128;

    const __bf16* qb = qT  + (size_t)b * NPTS * C4DIM;
    const __bf16* kb = kT  + (size_t)b * NPTS * C4DIM;
    const __bf16* vb = vin + (size_t)b * CDIM * NPTS;

    // DMA offsets (full K/V tiles staged by all 4 waves, swizzled groups)
    const int swz = (lane & 7) ^ ((lane >> 3) & 7);
    int koff[2], voff[4];
    #pragma unroll
    for (int s = 0; s < 2; s++) {
        int row = (2 * w + s) * 8 + (lane >> 3);
        koff[s] = row * 128 + swz * 16;
    }
    #pragma unroll
    for (int s = 0; s < 4; s++) {
        int row = (4 * w + s) * 8 + (lane >> 3);
        voff[s] = (c0 + row) * (NPTS * 2) + swz * 16;
    }

    // Q A-frags: rows i0 + 32r + 16rt + l16, k = kc*32 + quad*8
    bf16x8 aq[2][2];
    #pragma unroll
    for (int rt = 0; rt < 2; rt++)
        #pragma unroll
        for (int kc = 0; kc < 2; kc++)
            aq[rt][kc] = *(const bf16x8*)&qb[(size_t)(i0 + 32 * r + 16 * rt + l16) * C4DIM
                                             + kc * 32 + quad * 8];

    bf16x8 vone;
    #pragma unroll
    for (int u = 0; u < 8; u++) vone[u] = (__bf16)1.0f;

    f32x4 O[2][8], lacc[2];
    #pragma unroll
    for (int rt = 0; rt < 2; rt++) {
        lacc[rt] = (f32x4)(0.f);
        #pragma unroll
        for (int tc = 0; tc < 8; tc++) O[rt][tc] = (f32x4)(0.f);
    }

    // prologue DMA tile 0 -> buf 0
    {
        const char* kbase = (const char*)kb;
        const char* vbase = (const char*)vb;
        #pragma unroll
        for (int s = 0; s < 2; s++) async_cp16(kbase + koff[s], Kb + (2 * w + s) * 1024);
        #pragma unroll
        for (int s = 0; s < 4; s++) async_cp16(vbase + voff[s], Vb + (4 * w + s) * 1024);
    }

    // --- shared pieces ---
    bf16x8 apreg[2];           // P A-frags for the NEXT iter's PV (deferred)

    auto qk_exp_store = [&](int j0, const unsigned char* K) {
        // QK: S[rt][ct] = 32 rows x 32 cols (j slice jh)
        f32x4 S[2][2];
        #pragma unroll
        for (int rt = 0; rt < 2; rt++)
            #pragma unroll
            for (int ct = 0; ct < 2; ct++) S[rt][ct] = (f32x4)(0.f);
        #pragma unroll
        for (int kc = 0; kc < 2; kc++) {
            bf16x8 bk2[2];
            #pragma unroll
            for (int ct = 0; ct < 2; ct++) {
                int row = 32 * jh + 16 * ct + l16;
                int slot = (kc * 4 + quad) ^ (l16 & 7);
                bk2[ct] = *(const bf16x8*)(K + row * 128 + slot * 16);
            }
            #pragma unroll
            for (int rt = 0; rt < 2; rt++)
                #pragma unroll
                for (int ct = 0; ct < 2; ct++)
                    S[rt][ct] = __builtin_amdgcn_mfma_f32_16x16x32_bf16(
                        aq[rt][kc], bk2[ct], S[rt][ct], 0, 0, 0);
        }
        // P = exp(s - 32) = exp2(fma(s, log2e, -32*log2e)); b16 scatter
        #pragma unroll
        for (int rt = 0; rt < 2; rt++)
            #pragma unroll
            for (int ct = 0; ct < 2; ct++)
                #pragma unroll
                for (int r4 = 0; r4 < 4; r4++)
                    Ps[32 * r + 16 * rt + 4 * quad + r4][32 * jh + 16 * ct + l16] =
                        (__bf16)__builtin_amdgcn_exp2f(
                            __builtin_fmaf(S[rt][ct][r4], 1.44269504088896340736f,
                                           -46.16624130844683f));
        // prefetch ap for the deferred PV (same-wave in-order LDS RAW)
        #pragma unroll
        for (int rt = 0; rt < 2; rt++)
            apreg[rt] = *(const bf16x8*)((const char*)&Ps[32 * r + 16 * rt + l16][0]
                                         + jh * 64 + quad * 16);
    };

    auto pv_burst = [&](const unsigned char* V) {
        __builtin_amdgcn_s_setprio(1);
        #pragma unroll
        for (int tc = 0; tc < 8; tc++) {
            int row = 16 * tc + l16;
            int slot = (jh * 4 + quad) ^ (l16 & 7);
            bf16x8 bv2 = *(const bf16x8*)(V + row * 128 + slot * 16);
            #pragma unroll
            for (int rt = 0; rt < 2; rt++)
                O[rt][tc] = __builtin_amdgcn_mfma_f32_16x16x32_bf16(
                    apreg[rt], bv2, O[rt][tc], 0, 0, 0);
        }
        #pragma unroll
        for (int rt = 0; rt < 2; rt++)
            lacc[rt] = __builtin_amdgcn_mfma_f32_16x16x32_bf16(apreg[rt], vone,
                                                               lacc[rt], 0, 0, 0);
        __builtin_amdgcn_s_setprio(0);
    };

    // --- peeled tile 0: QK/exp/store only (no PV yet) ---
    __syncthreads();   // drains DMA(0) into bufs[0]
    {
        // issue DMA(1) -> bufs[1]
        const char* kbase = (const char*)kb + (size_t)64 * (C4DIM * 2);
        const char* vbase = (const char*)vb + (size_t)64 * 2;
        #pragma unroll
        for (int s = 0; s < 2; s++) async_cp16(kbase + koff[s], Kb + 8192 + (2 * w + s) * 1024);
        #pragma unroll
        for (int s = 0; s < 4; s++) async_cp16(vbase + voff[s], Vb + 16384 + (4 * w + s) * 1024);
    }
    qk_exp_store(0, Kb);

    // --- main loop: tiles 1..63; PV(t-1) at top, QK(t) after barrier ---
    int p = 1;
    for (int j0 = 64; j0 < NPTS; j0 += 64, p ^= 1) {
        // PV for previous tile: V[p^1], apreg (no LDS-write deps)
        pv_burst(Vb + (p ^ 1) * 16384);

        __syncthreads();   // drains DMA(t) into bufs[p]; V/K[p^1] now free

        if (j0 + 64 < NPTS) {
            const char* kbase = (const char*)kb + (size_t)(j0 + 64) * (C4DIM * 2);
            const char* vbase = (const char*)vb + (size_t)(j0 + 64) * 2;
            unsigned char* Kd = Kb + (p ^ 1) * 8192;
            unsigned char* Vd = Vb + (p ^ 1) * 16384;
            #pragma unroll
            for (int s = 0; s < 2; s++) async_cp16(kbase + koff[s], Kd + (2 * w + s) * 1024);
            #pragma unroll
            for (int s = 0; s < 4; s++) async_cp16(vbase + voff[s], Vd + (4 * w + s) * 1024);
        }

        qk_exp_store(j0, Kb + p * 8192);
    }

    // --- epilogue PV for the last tile (63, resident in bufs[1]) ---
    pv_burst(Vb + 16384);

    // ---- epilogue: combine j-half partials, gamma/l scale, transpose, +x
    __syncthreads();   // all K/V/Ps reads done; sm reusable
    const float g = gptr[0];

    if (jh == 1) {
        float* dst = (float*)(sm + (size_t)(r * 64 + lane) * 272);
        #pragma unroll
        for (int rt = 0; rt < 2; rt++)
            #pragma unroll
            for (int tc = 0; tc < 8; tc++)
                *(f32x4*)(dst + (rt * 8 + tc) * 4) = O[rt][tc];
        if (l16 == 0) {
            #pragma unroll
            for (int rt = 0; rt < 2; rt++)
                #pragma unroll
                for (int r4 = 0; r4 < 4; r4++)
                    Lp[32 * r + 16 * rt + 4 * quad + r4] = lacc[rt][r4];
        }
    }
    __syncthreads();

    float inv[2][4];
    if (jh == 0) {
        const float* src = (const float*)(sm + (size_t)(r * 64 + lane) * 272);
        #pragma unroll
        for (int rt = 0; rt < 2; rt++)
            #pragma unroll
            for (int tc = 0; tc < 8; tc++)
                O[rt][tc] += *(const f32x4*)(src + (rt * 8 + tc) * 4);
        #pragma unroll
        for (int rt = 0; rt < 2; rt++)
            #pragma unroll
            for (int r4 = 0; r4 < 4; r4++) {
                float ls = lacc[rt][r4] + Lp[32 * r + 16 * rt + 4 * quad + r4];
                inv[rt][r4] = g / ls;
            }
    }
    __syncthreads();   // partial reads done; OTa overlays same bytes

    if (jh == 0) {
        #pragma unroll
        for (int rt = 0; rt < 2; rt++)
            #pragma unroll
            for (int tc = 0; tc < 8; tc++) {
                int c = 16 * tc + l16;
                float4 f;
                f.x = O[rt][tc][0] * inv[rt][0];
                f.y = O[rt][tc][1] * inv[rt][1];
                f.z = O[rt][tc][2] * inv[rt][2];
                f.w = O[rt][tc][3] * inv[rt][3];
                *(float4*)&OTa[c][32 * r + 16 * rt + 4 * quad] = f;
            }
    }
    __syncthreads();

    const float* xb = xin + (size_t)b * CDIM * NPTS;
    float*       ob = out + (size_t)b * CDIM * NPTS;
    #pragma unroll
    for (int s = 0; s < 8; s++) {
        int lin = t + 256 * s;            // 0..2047
        int c = lin >> 4, col = (lin & 15) * 4;
        size_t gi = (size_t)(c0 + c) * NPTS + i0 + col;
        float4 ov = *(const float4*)&OTa[c][col];
        float4 xv = *(const float4*)&xb[gi];
        float4 rr;
        rr.x = ov.x + xv.x; rr.y = ov.y + xv.y;
        rr.z = ov.z + xv.z; rr.w = ov.w + xv.w;
        *(float4*)&ob[gi] = rr;
    }
}

extern "C" void kernel_launch(void* const* d_in, const int* in_sizes, int n_in,
                              void* d_out, int out_size, void* d_ws, size_t ws_size,
                              hipStream_t stream) {
    const float* x     = (const float*)d_in[0];
    const float* Wq    = (const float*)d_in[1];
    const float* bq    = (const float*)d_in[2];
    const float* Wk    = (const float*)d_in[3];
    const float* bk    = (const float*)d_in[4];
    const float* Wv    = (const float*)d_in[5];
    const float* bv    = (const float*)d_in[6];
    const float* gamma = (const float*)d_in[7];

    const int B = 4;
    __bf16* qT  = (__bf16*)d_ws;                        // 2 MB
    __bf16* kT  = qT + (size_t)B * NPTS * C4DIM;        // 2 MB
    __bf16* v   = kT + (size_t)B * NPTS * C4DIM;        // 8 MB
    __bf16* wsz = v  + (size_t)B * CDIM * NPTS;         // 192 KB (swizzled bf16 W)

    wprep_kernel<<<96, 256, 0, stream>>>(Wq, Wk, Wv, wsz);

    proj_kernel<<<dim3(NPTS/32, B), 256, 0, stream>>>(
        x, bq, bk, bv, wsz, qT, kT, v);

    attn_kernel<<<dim3(NPTS/64, CDIM/128, B), 256, 0, stream>>>(
        qT, kT, v, x, gamma, (float*)d_out);
}

// Round 7
// 162.554 us; speedup vs baseline: 1.6435x; 1.0045x over previous
//
#include <hip/hip_runtime.h>

#define NPTS 4096
#define CDIM 256
#define C4DIM 64

typedef __bf16 bf16x8 __attribute__((ext_vector_type(8)));
typedef short  s16x4  __attribute__((ext_vector_type(4)));
typedef float  f32x4  __attribute__((ext_vector_type(4)));

// gfx950 carries v_mfma_f32_16x16x16_bf16 (cdna4_isa §10, A/B = 2 VGPRs = 4
// bf16). Builtin name is the gfx90a-era _1k spelling; called unconditionally
// (host pass defers aux-target builtins — #if __has_builtin breaks host).
#define MFMA16(a, b, c) __builtin_amdgcn_mfma_f32_16x16x16bf16_1k((a), (b), (c), 0, 0, 0)

__device__ __forceinline__ void async_cp16(const void* g, void* l) {
    __builtin_amdgcn_global_load_lds(
        (const __attribute__((address_space(1))) void*)g,
        (__attribute__((address_space(3))) void*)l, 16, 0, 0);
}

// ---------------------------------------------------------------------------
// W prep: fp32 -> bf16, rows [Wq(64) | Wk(64) | Wv(256)] = 384 x 256,
// with 16B-group swizzle within each 512B row: phys_group = g ^ (row & 7).
// (verbatim, HW-verified)
// ---------------------------------------------------------------------------
__global__ __launch_bounds__(256) void wprep_kernel(
    const float* __restrict__ Wq, const float* __restrict__ Wk,
    const float* __restrict__ Wv, __bf16* __restrict__ wsz)
{
    int idx = blockIdx.x * 256 + threadIdx.x;   // 0..24575
    int row = idx >> 6;                         // 0..383
    int l   = idx & 63;                         // float4 index within row
    const float* src;
    if (row < 64)       src = Wq + (size_t)row * CDIM;
    else if (row < 128) src = Wk + (size_t)(row - 64) * CDIM;
    else                src = Wv + (size_t)(row - 128) * CDIM;
    float4 f = *(const float4*)&src[l * 4];
    int g  = l >> 1;                 // logical 16B group 0..31
    int gp = g ^ (row & 7);          // physical slot
    union { __bf16 h[4]; uint2 u; } pk;
    pk.h[0] = (__bf16)f.x; pk.h[1] = (__bf16)f.y;
    pk.h[2] = (__bf16)f.z; pk.h[3] = (__bf16)f.w;
    *(uint2*)&wsz[(size_t)row * CDIM + gp * 8 + (l & 1) * 4] = pk.u;
}

// ---------------------------------------------------------------------------
// MFMA projection (round-7 version, verified -4.6us vs r6): 32-n tiles,
// grid (NPTS/32, B), block 256; LDS 64KB -> 2 blocks/CU.
// ---------------------------------------------------------------------------
__global__ __launch_bounds__(256, 2) void proj_kernel(
    const float* __restrict__ x,
    const float* __restrict__ bq, const float* __restrict__ bk,
    const float* __restrict__ bv, const __bf16* __restrict__ wsz,
    __bf16* __restrict__ qT, __bf16* __restrict__ kT, __bf16* __restrict__ vo)
{
    __shared__ __align__(16) unsigned char sm[65536];
    auto Xs = (float (*)[33])sm;                 // [256][33] fp32, dies after A-build

    const int t    = threadIdx.x;
    const int w    = t >> 6;
    const int lane = t & 63;
    const int quad = lane >> 4;
    const int l16  = lane & 15;
    const int nq   = w >> 1;
    const int th   = w & 1;

    const int n0 = blockIdx.x * 32;
    const int b  = blockIdx.y;

    #pragma unroll
    for (int s = 0; s < 8; s++) {
        int lin = t + 256 * s;
        int c = lin >> 3, n4 = (lin & 7) * 4;
        *(float4*)&Xs[c][n4] =
            *(const float4*)&x[((size_t)b * CDIM + c) * NPTS + n0 + n4];
    }
    __syncthreads();

    bf16x8 af[8];
    #pragma unroll
    for (int kc = 0; kc < 8; kc++) {
        union { __bf16 h8[8]; bf16x8 v; } pk;
        #pragma unroll
        for (int u = 0; u < 8; u++)
            pk.h8[u] = (__bf16)Xs[kc * 32 + quad * 8 + u][16 * nq + l16];
        af[kc] = pk.v;
    }
    __syncthreads();

    const int lhalf = lane >> 5;
    const int rlow  = (2 * w + lhalf) & 7;
    const int slane = ((lane & 31) ^ rlow) * 8;

    #pragma unroll
    for (int s = 0; s < 8; s++)
        async_cp16(wsz + (size_t)(8 * s + 2 * w + lhalf) * CDIM + slane,
                   sm + (s * 4 + w) * 1024);

    f32x4 acc[6][2];
    #pragma unroll
    for (int ot = 0; ot < 6; ot++) {
        acc[ot][0] = (f32x4)(0.f);
        acc[ot][1] = (f32x4)(0.f);
    }

    #pragma unroll
    for (int ot = 0; ot < 6; ot++) {
        __syncthreads();
        if (ot < 5) {
            #pragma unroll
            for (int s = 0; s < 8; s++)
                async_cp16(wsz + (size_t)((ot + 1) * 64 + 8 * s + 2 * w + lhalf) * CDIM + slane,
                           sm + ((ot + 1) & 1) * 32768 + (s * 4 + w) * 1024);
        }
        const unsigned char* Wp = sm + (ot & 1) * 32768;
        #pragma unroll
        for (int kc = 0; kc < 8; kc++) {
            bf16x8 bw[2];
            #pragma unroll
            for (int tcl = 0; tcl < 2; tcl++)
                bw[tcl] = *(const bf16x8*)(Wp + (16 * (2 * th + tcl) + l16) * 512
                                              + (((kc * 4 + quad) ^ (l16 & 7)) << 4));
            #pragma unroll
            for (int tcl = 0; tcl < 2; tcl++)
                acc[ot][tcl] = __builtin_amdgcn_mfma_f32_16x16x32_bf16(
                    af[kc], bw[tcl], acc[ot][tcl], 0, 0, 0);
        }
    }

    {
        auto OT = (float (*)[68])sm;
        #pragma unroll
        for (int ot = 0; ot < 2; ot++) {
            __syncthreads();
            const float* bias = ot ? bk : bq;
            #pragma unroll
            for (int tcl = 0; tcl < 2; tcl++) {
                float bs = bias[16 * (2 * th + tcl) + l16];
                #pragma unroll
                for (int r4 = 0; r4 < 4; r4++)
                    OT[16 * nq + 4 * quad + r4][16 * (2 * th + tcl) + l16] =
                        acc[ot][tcl][r4] + bs;
            }
            __syncthreads();
            __bf16* outp = (ot == 0 ? qT : kT) + (size_t)b * NPTS * C4DIM;
            int n = t >> 3, op = (t & 7) * 8;
            f32x4 o0 = *(const f32x4*)&OT[n][op];
            f32x4 o1 = *(const f32x4*)&OT[n][op + 4];
            union { __bf16 h[8]; uint4 u; } pk;
            #pragma unroll
            for (int u2 = 0; u2 < 4; u2++) {
                pk.h[u2]     = (__bf16)o0[u2];
                pk.h[u2 + 4] = (__bf16)o1[u2];
            }
            *(uint4*)&outp[(size_t)(n0 + n) * C4DIM + op] = pk.u;
        }
    }
    {
        auto OTv = (float (*)[36])sm;
        #pragma unroll
        for (int ot = 2; ot < 6; ot++) {
            __syncthreads();
            #pragma unroll
            for (int tcl = 0; tcl < 2; tcl++) {
                float bs = bv[(ot - 2) * 64 + 16 * (2 * th + tcl) + l16];
                f32x4 v4 = acc[ot][tcl];
                v4[0] += bs; v4[1] += bs; v4[2] += bs; v4[3] += bs;
                *(f32x4*)&OTv[16 * (2 * th + tcl) + l16][16 * nq + 4 * quad] = v4;
            }
            __syncthreads();
            int cl = t >> 2, np = (t & 3) * 8;
            int ch = (ot - 2) * 64 + cl;
            f32x4 o0 = *(const f32x4*)&OTv[cl][np];
            f32x4 o1 = *(const f32x4*)&OTv[cl][np + 4];
            union { __bf16 h[8]; uint4 u; } pk;
            #pragma unroll
            for (int u2 = 0; u2 < 4; u2++) {
                pk.h[u2]     = (__bf16)o0[u2];
                pk.h[u2 + 4] = (__bf16)o1[u2];
            }
            *(uint4*)&vo[((size_t)b * CDIM + ch) * NPTS + n0 + np] = pk.u;
        }
    }
}

// ---------------------------------------------------------------------------
// MFMA flash attention, round 13 (= r12 + host-pass compile fix):
// in-register P, no Ps LDS buffer. r9 skeleton (DMA-staged K/V double-buffer,
// 64 barriers, same epilogue). Swapped QK (verified r7/r8): S' = mfma(K, Q)
// puts P[i=l16][j=4*quad+r4] in-lane = A-frag layout of the k=16 MFMA, so P
// feeds PV directly after an in-register f32->bf16 pack. The 16 ds_write_b16
// + 2 ds_read_b128 P round-trip per wave-iter (~35% of the ~71%-busy LDS
// pipe) is deleted. V consumed as ds_read_b64 B-frags (same bytes/swizzle).
// O/lacc lane layouts identical to r9 -> epilogue verbatim. exp2-fma +
// setprio kept (verified r9).
// ---------------------------------------------------------------------------
__global__ __launch_bounds__(256, 2) void attn_kernel(
    const __bf16* __restrict__ qT, const __bf16* __restrict__ kT,
    const __bf16* __restrict__ vin, const float* __restrict__ xin,
    const float* __restrict__ gptr, float* __restrict__ out)
{
    __shared__ __align__(16) unsigned char sm[49152];
    unsigned char* Kb = sm;                  // [2][64 rows][128 B] = 16384
    unsigned char* Vb = sm + 16384;          // [2][128 rows][128 B] = 32768
    // epilogue overlays (after barrier): Opart 128x272B, Lp at 34816

    const int t    = threadIdx.x;
    const int w    = t >> 6;
    const int lane = t & 63;
    const int quad = lane >> 4;
    const int l16  = lane & 15;
    const int r    = w >> 1;    // i row half
    const int jh   = w & 1;     // j half

    const int b  = blockIdx.z;
    const int i0 = blockIdx.x * 64;
    const int c0 = blockIdx.y * 128;

    const __bf16* qb = qT  + (size_t)b * NPTS * C4DIM;
    const __bf16* kb = kT  + (size_t)b * NPTS * C4DIM;
    const __bf16* vb = vin + (size_t)b * CDIM * NPTS;

    // DMA offsets (full K/V tiles staged by all 4 waves, swizzled groups)
    const int swz = (lane & 7) ^ ((lane >> 3) & 7);
    int koff[2], voff[4];
    #pragma unroll
    for (int s = 0; s < 2; s++) {
        int row = (2 * w + s) * 8 + (lane >> 3);
        koff[s] = row * 128 + swz * 16;
    }
    #pragma unroll
    for (int s = 0; s < 4; s++) {
        int row = (4 * w + s) * 8 + (lane >> 3);
        voff[s] = (c0 + row) * (NPTS * 2) + swz * 16;
    }

    // Q B-frags (swapped QK): lane l16 = i col, k = c = kc*32 + quad*8
    bf16x8 aq[2][2];
    #pragma unroll
    for (int rt = 0; rt < 2; rt++)
        #pragma unroll
        for (int kc = 0; kc < 2; kc++)
            aq[rt][kc] = *(const bf16x8*)&qb[(size_t)(i0 + 32 * r + 16 * rt + l16) * C4DIM
                                             + kc * 32 + quad * 8];

    s16x4 vone4;
    {
        union { __bf16 h[4]; s16x4 s; } o;
        #pragma unroll
        for (int u = 0; u < 4; u++) o.h[u] = (__bf16)1.0f;
        vone4 = o.s;
    }

    f32x4 O[2][8], lacc[2];
    #pragma unroll
    for (int rt = 0; rt < 2; rt++) {
        lacc[rt] = (f32x4)(0.f);
        #pragma unroll
        for (int tc = 0; tc < 8; tc++) O[rt][tc] = (f32x4)(0.f);
    }

    // prologue DMA tile 0 -> buf 0
    {
        const char* kbase = (const char*)kb;
        const char* vbase = (const char*)vb;
        #pragma unroll
        for (int s = 0; s < 2; s++) async_cp16(kbase + koff[s], Kb + (2 * w + s) * 1024);
        #pragma unroll
        for (int s = 0; s < 4; s++) async_cp16(vbase + voff[s], Vb + (4 * w + s) * 1024);
    }

    int p = 0;
    for (int j0 = 0; j0 < NPTS; j0 += 64, p ^= 1) {
        __syncthreads();   // drains DMA into buf p; buf p^1 reads done

        if (j0 + 64 < NPTS) {
            const char* kbase = (const char*)kb + (size_t)(j0 + 64) * (C4DIM * 2);
            const char* vbase = (const char*)vb + (size_t)(j0 + 64) * 2;
            unsigned char* Kd = Kb + (p ^ 1) * 8192;
            unsigned char* Vd = Vb + (p ^ 1) * 16384;
            #pragma unroll
            for (int s = 0; s < 2; s++) async_cp16(kbase + koff[s], Kd + (2 * w + s) * 1024);
            #pragma unroll
            for (int s = 0; s < 4; s++) async_cp16(vbase + voff[s], Vd + (4 * w + s) * 1024);
        }

        const unsigned char* K = Kb + p * 8192;
        const unsigned char* V = Vb + p * 16384;

        // ---- swapped QK: S'[jt][it], lane holds S[i=16it+l16][j=16jt+4quad+r4]
        f32x4 S[2][2];
        #pragma unroll
        for (int jt = 0; jt < 2; jt++)
            #pragma unroll
            for (int it = 0; it < 2; it++) S[jt][it] = (f32x4)(0.f);
        #pragma unroll
        for (int kc = 0; kc < 2; kc++) {
            bf16x8 ka[2];    // A-frag: lane l16 = j row, k = c = kc*32+quad*8
            #pragma unroll
            for (int jt = 0; jt < 2; jt++) {
                int row = 32 * jh + 16 * jt + l16;
                int slot = (kc * 4 + quad) ^ (l16 & 7);
                ka[jt] = *(const bf16x8*)(K + row * 128 + slot * 16);
            }
            #pragma unroll
            for (int jt = 0; jt < 2; jt++)
                #pragma unroll
                for (int it = 0; it < 2; it++)
                    S[jt][it] = __builtin_amdgcn_mfma_f32_16x16x32_bf16(
                        ka[jt], aq[it][kc], S[jt][it], 0, 0, 0);
        }

        // ---- P = exp(s-32) packed in-register: pa[it][jt] = A-frag of k=16 PV
        union { __bf16 h[4]; s16x4 s; } pa[2][2];
        #pragma unroll
        for (int it = 0; it < 2; it++)
            #pragma unroll
            for (int jt = 0; jt < 2; jt++)
                #pragma unroll
                for (int r4 = 0; r4 < 4; r4++)
                    pa[it][jt].h[r4] = (__bf16)__builtin_amdgcn_exp2f(
                        __builtin_fmaf(S[jt][it][r4], 1.44269504088896340736f,
                                       -46.16624130844683f));

        // ---- PV: two k=16 MFMAs per c-tile (V as b64 B-frags, no P LDS)
        __builtin_amdgcn_s_setprio(1);
        #pragma unroll
        for (int jt = 0; jt < 2; jt++) {
            #pragma unroll
            for (int tc = 0; tc < 8; tc++) {
                int row = 16 * tc + l16;
                int g = (4 * jh + 2 * jt + (quad >> 1)) ^ (l16 & 7);
                s16x4 vv = *(const s16x4*)(V + row * 128 + g * 16 + (quad & 1) * 8);
                #pragma unroll
                for (int it = 0; it < 2; it++)
                    O[it][tc] = MFMA16(pa[it][jt].s, vv, O[it][tc]);
            }
            #pragma unroll
            for (int it = 0; it < 2; it++)
                lacc[it] = MFMA16(pa[it][jt].s, vone4, lacc[it]);
        }
        __builtin_amdgcn_s_setprio(0);
    }

    // ---- epilogue: combine j-half partials, gamma/l scale, transpose, +x
    __syncthreads();   // all K/V reads done; sm reusable
    const float g = gptr[0];
    float* Lp = (float*)(sm + 34816);

    if (jh == 1) {
        float* dst = (float*)(sm + (size_t)(r * 64 + lane) * 272);
        #pragma unroll
        for (int rt = 0; rt < 2; rt++)
            #pragma unroll
            for (int tc = 0; tc < 8; tc++)
                *(f32x4*)(dst + (rt * 8 + tc) * 4) = O[rt][tc];
        if (l16 == 0) {
            #pragma unroll
            for (int rt = 0; rt < 2; rt++)
                #pragma unroll
                for (int r4 = 0; r4 < 4; r4++)
                    Lp[32 * r + 16 * rt + 4 * quad + r4] = lacc[rt][r4];
        }
    }
    __syncthreads();

    float inv[2][4];
    if (jh == 0) {
        const float* src = (const float*)(sm + (size_t)(r * 64 + lane) * 272);
        #pragma unroll
        for (int rt = 0; rt < 2; rt++)
            #pragma unroll
            for (int tc = 0; tc < 8; tc++)
                O[rt][tc] += *(const f32x4*)(src + (rt * 8 + tc) * 4);
        #pragma unroll
        for (int rt = 0; rt < 2; rt++)
            #pragma unroll
            for (int r4 = 0; r4 < 4; r4++) {
                float ls = lacc[rt][r4] + Lp[32 * r + 16 * rt + 4 * quad + r4];
                inv[rt][r4] = g / ls;
            }
    }
    __syncthreads();   // partial reads done; OTa overlays same bytes

    auto OTa = (float (*)[68])sm;            // [128][68] fp32
    if (jh == 0) {
        #pragma unroll
        for (int rt = 0; rt < 2; rt++)
            #pragma unroll
            for (int tc = 0; tc < 8; tc++) {
                int c = 16 * tc + l16;
                float4 f;
                f.x = O[rt][tc][0] * inv[rt][0];
                f.y = O[rt][tc][1] * inv[rt][1];
                f.z = O[rt][tc][2] * inv[rt][2];
                f.w = O[rt][tc][3] * inv[rt][3];
                *(float4*)&OTa[c][32 * r + 16 * rt + 4 * quad] = f;
            }
    }
    __syncthreads();

    const float* xb = xin + (size_t)b * CDIM * NPTS;
    float*       ob = out + (size_t)b * CDIM * NPTS;
    #pragma unroll
    for (int s = 0; s < 8; s++) {
        int lin = t + 256 * s;            // 0..2047
        int c = lin >> 4, col = (lin & 15) * 4;
        size_t gi = (size_t)(c0 + c) * NPTS + i0 + col;
        float4 ov = *(const float4*)&OTa[c][col];
        float4 xv = *(const float4*)&xb[gi];
        float4 rr;
        rr.x = ov.x + xv.x; rr.y = ov.y + xv.y;
        rr.z = ov.z + xv.z; rr.w = ov.w + xv.w;
        *(float4*)&ob[gi] = rr;
    }
}

extern "C" void kernel_launch(void* const* d_in, const int* in_sizes, int n_in,
                              void* d_out, int out_size, void* d_ws, size_t ws_size,
                              hipStream_t stream) {
    const float* x     = (const float*)d_in[0];
    const float* Wq    = (const float*)d_in[1];
    const float* bq    = (const float*)d_in[2];
    const float* Wk    = (const float*)d_in[3];
    const float* bk    = (const float*)d_in[4];
    const float* Wv    = (const float*)d_in[5];
    const float* bv    = (const float*)d_in[6];
    const float* gamma = (const float*)d_in[7];

    const int B = 4;
    __bf16* qT  = (__bf16*)d_ws;                        // 2 MB
    __bf16* kT  = qT + (size_t)B * NPTS * C4DIM;        // 2 MB
    __bf16* v   = kT + (size_t)B * NPTS * C4DIM;        // 8 MB
    __bf16* wsz = v  + (size_t)B * CDIM * NPTS;         // 192 KB (swizzled bf16 W)

    wprep_kernel<<<96, 256, 0, stream>>>(Wq, Wk, Wv, wsz);

    proj_kernel<<<dim3(NPTS/32, B), 256, 0, stream>>>(
        x, bq, bk, bv, wsz, qT, kT, v);

    attn_kernel<<<dim3(NPTS/64, CDIM/128, B), 256, 0, stream>>>(
        qT, kT, v, x, gamma, (float*)d_out);
}

// Round 8
// 153.133 us; speedup vs baseline: 1.7446x; 1.0615x over previous
//
#include <hip/hip_runtime.h>

#define NPTS 4096
#define CDIM 256
#define C4DIM 64

typedef __bf16 bf16x8 __attribute__((ext_vector_type(8)));
typedef float  f32x4  __attribute__((ext_vector_type(4)));

__device__ __forceinline__ void async_cp16(const void* g, void* l) {
    __builtin_amdgcn_global_load_lds(
        (const __attribute__((address_space(1))) void*)g,
        (__attribute__((address_space(3))) void*)l, 16, 0, 0);
}

// v_cvt_pk_bf16_f32: D.lo16 = bf16(S0), D.hi16 = bf16(S1). No builtin on
// gfx950 (learn_hip m240) -> inline asm.
__device__ __forceinline__ unsigned cvt_pk_bf16(float lo, float hi) {
    unsigned r;
    asm("v_cvt_pk_bf16_f32 %0, %1, %2" : "=v"(r) : "v"(lo), "v"(hi));
    return r;
}

// ---------------------------------------------------------------------------
// W prep: fp32 -> bf16, rows [Wq(64) | Wk(64) | Wv(256)] = 384 x 256,
// with 16B-group swizzle within each 512B row: phys_group = g ^ (row & 7).
// (verbatim, HW-verified)
// ---------------------------------------------------------------------------
__global__ __launch_bounds__(256) void wprep_kernel(
    const float* __restrict__ Wq, const float* __restrict__ Wk,
    const float* __restrict__ Wv, __bf16* __restrict__ wsz)
{
    int idx = blockIdx.x * 256 + threadIdx.x;   // 0..24575
    int row = idx >> 6;                         // 0..383
    int l   = idx & 63;                         // float4 index within row
    const float* src;
    if (row < 64)       src = Wq + (size_t)row * CDIM;
    else if (row < 128) src = Wk + (size_t)(row - 64) * CDIM;
    else                src = Wv + (size_t)(row - 128) * CDIM;
    float4 f = *(const float4*)&src[l * 4];
    int g  = l >> 1;                 // logical 16B group 0..31
    int gp = g ^ (row & 7);          // physical slot
    union { __bf16 h[4]; uint2 u; } pk;
    pk.h[0] = (__bf16)f.x; pk.h[1] = (__bf16)f.y;
    pk.h[2] = (__bf16)f.z; pk.h[3] = (__bf16)f.w;
    *(uint2*)&wsz[(size_t)row * CDIM + gp * 8 + (l & 1) * 4] = pk.u;
}

// ---------------------------------------------------------------------------
// MFMA projection (round-7 version, verified -4.6us vs r6): 32-n tiles,
// grid (NPTS/32, B), block 256; LDS 64KB -> 2 blocks/CU.
// ---------------------------------------------------------------------------
__global__ __launch_bounds__(256, 2) void proj_kernel(
    const float* __restrict__ x,
    const float* __restrict__ bq, const float* __restrict__ bk,
    const float* __restrict__ bv, const __bf16* __restrict__ wsz,
    __bf16* __restrict__ qT, __bf16* __restrict__ kT, __bf16* __restrict__ vo)
{
    __shared__ __align__(16) unsigned char sm[65536];
    auto Xs = (float (*)[33])sm;                 // [256][33] fp32, dies after A-build

    const int t    = threadIdx.x;
    const int w    = t >> 6;
    const int lane = t & 63;
    const int quad = lane >> 4;
    const int l16  = lane & 15;
    const int nq   = w >> 1;
    const int th   = w & 1;

    const int n0 = blockIdx.x * 32;
    const int b  = blockIdx.y;

    #pragma unroll
    for (int s = 0; s < 8; s++) {
        int lin = t + 256 * s;
        int c = lin >> 3, n4 = (lin & 7) * 4;
        *(float4*)&Xs[c][n4] =
            *(const float4*)&x[((size_t)b * CDIM + c) * NPTS + n0 + n4];
    }
    __syncthreads();

    bf16x8 af[8];
    #pragma unroll
    for (int kc = 0; kc < 8; kc++) {
        union { __bf16 h8[8]; bf16x8 v; } pk;
        #pragma unroll
        for (int u = 0; u < 8; u++)
            pk.h8[u] = (__bf16)Xs[kc * 32 + quad * 8 + u][16 * nq + l16];
        af[kc] = pk.v;
    }
    __syncthreads();

    const int lhalf = lane >> 5;
    const int rlow  = (2 * w + lhalf) & 7;
    const int slane = ((lane & 31) ^ rlow) * 8;

    #pragma unroll
    for (int s = 0; s < 8; s++)
        async_cp16(wsz + (size_t)(8 * s + 2 * w + lhalf) * CDIM + slane,
                   sm + (s * 4 + w) * 1024);

    f32x4 acc[6][2];
    #pragma unroll
    for (int ot = 0; ot < 6; ot++) {
        acc[ot][0] = (f32x4)(0.f);
        acc[ot][1] = (f32x4)(0.f);
    }

    #pragma unroll
    for (int ot = 0; ot < 6; ot++) {
        __syncthreads();
        if (ot < 5) {
            #pragma unroll
            for (int s = 0; s < 8; s++)
                async_cp16(wsz + (size_t)((ot + 1) * 64 + 8 * s + 2 * w + lhalf) * CDIM + slane,
                           sm + ((ot + 1) & 1) * 32768 + (s * 4 + w) * 1024);
        }
        const unsigned char* Wp = sm + (ot & 1) * 32768;
        #pragma unroll
        for (int kc = 0; kc < 8; kc++) {
            bf16x8 bw[2];
            #pragma unroll
            for (int tcl = 0; tcl < 2; tcl++)
                bw[tcl] = *(const bf16x8*)(Wp + (16 * (2 * th + tcl) + l16) * 512
                                              + (((kc * 4 + quad) ^ (l16 & 7)) << 4));
            #pragma unroll
            for (int tcl = 0; tcl < 2; tcl++)
                acc[ot][tcl] = __builtin_amdgcn_mfma_f32_16x16x32_bf16(
                    af[kc], bw[tcl], acc[ot][tcl], 0, 0, 0);
        }
    }

    {
        auto OT = (float (*)[68])sm;
        #pragma unroll
        for (int ot = 0; ot < 2; ot++) {
            __syncthreads();
            const float* bias = ot ? bk : bq;
            #pragma unroll
            for (int tcl = 0; tcl < 2; tcl++) {
                float bs = bias[16 * (2 * th + tcl) + l16];
                #pragma unroll
                for (int r4 = 0; r4 < 4; r4++)
                    OT[16 * nq + 4 * quad + r4][16 * (2 * th + tcl) + l16] =
                        acc[ot][tcl][r4] + bs;
            }
            __syncthreads();
            __bf16* outp = (ot == 0 ? qT : kT) + (size_t)b * NPTS * C4DIM;
            int n = t >> 3, op = (t & 7) * 8;
            f32x4 o0 = *(const f32x4*)&OT[n][op];
            f32x4 o1 = *(const f32x4*)&OT[n][op + 4];
            union { __bf16 h[8]; uint4 u; } pk;
            #pragma unroll
            for (int u2 = 0; u2 < 4; u2++) {
                pk.h[u2]     = (__bf16)o0[u2];
                pk.h[u2 + 4] = (__bf16)o1[u2];
            }
            *(uint4*)&outp[(size_t)(n0 + n) * C4DIM + op] = pk.u;
        }
    }
    {
        auto OTv = (float (*)[36])sm;
        #pragma unroll
        for (int ot = 2; ot < 6; ot++) {
            __syncthreads();
            #pragma unroll
            for (int tcl = 0; tcl < 2; tcl++) {
                float bs = bv[(ot - 2) * 64 + 16 * (2 * th + tcl) + l16];
                f32x4 v4 = acc[ot][tcl];
                v4[0] += bs; v4[1] += bs; v4[2] += bs; v4[3] += bs;
                *(f32x4*)&OTv[16 * (2 * th + tcl) + l16][16 * nq + 4 * quad] = v4;
            }
            __syncthreads();
            int cl = t >> 2, np = (t & 3) * 8;
            int ch = (ot - 2) * 64 + cl;
            f32x4 o0 = *(const f32x4*)&OTv[cl][np];
            f32x4 o1 = *(const f32x4*)&OTv[cl][np + 4];
            union { __bf16 h[8]; uint4 u; } pk;
            #pragma unroll
            for (int u2 = 0; u2 < 4; u2++) {
                pk.h[u2]     = (__bf16)o0[u2];
                pk.h[u2 + 4] = (__bf16)o1[u2];
            }
            *(uint4*)&vo[((size_t)b * CDIM + ch) * NPTS + n0 + np] = pk.u;
        }
    }
}

// ---------------------------------------------------------------------------
// MFMA flash attention, round 14: in-register P + k32 PV via permlane.
// r9 skeleton (DMA-staged K/V double-buffer, 64 barriers, same epilogue).
// Swapped QK (r13-verified): lane holds P[i=l16][j=16jt+4quad+r4].
// k32 PV A-frag needs j=8*quad..8*quad+7 per lane -> redistribute across
// quads with gfx950 row-swap primitives:
//   (t0,t1) = permlane32_swap(A,B):  t0=[a0,a1,b0,b1], t1=[a2,a3,b2,b3]
//   (X, Y ) = permlane16_swap(t0,t1): X=[a0,a2,b0,b2],  Y=[a1,a3,b1,b3]
// with A=pack(jt0 pair h), B=pack(jt1 pair h) -> X_h/Y_h are exactly frag
// u32s {k=8q+2h,+1} / {k=8q+4+2h,+1}; i=l16 preserved (all quads share i).
// PV: 16 k32 MFMAs + b128 V reads (r9-verified swizzle, ~2-way banks) --
// fixes r13's 8.45M conflicts AND halves r13's PV matrix-pipe cycles
// (k16 costs same ~4.8cyc as k32, measured r13 MfmaUtil 26->45 at flat time).
// exp2-fma + setprio kept.
// ---------------------------------------------------------------------------
__global__ __launch_bounds__(256, 2) void attn_kernel(
    const __bf16* __restrict__ qT, const __bf16* __restrict__ kT,
    const __bf16* __restrict__ vin, const float* __restrict__ xin,
    const float* __restrict__ gptr, float* __restrict__ out)
{
    __shared__ __align__(16) unsigned char sm[49152];
    unsigned char* Kb = sm;                  // [2][64 rows][128 B] = 16384
    unsigned char* Vb = sm + 16384;          // [2][128 rows][128 B] = 32768
    // epilogue overlays (after barrier): Opart 128x272B, Lp at 34816

    const int t    = threadIdx.x;
    const int w    = t >> 6;
    const int lane = t & 63;
    const int quad = lane >> 4;
    const int l16  = lane & 15;
    const int r    = w >> 1;    // i row half
    const int jh   = w & 1;     // j half

    const int b  = blockIdx.z;
    const int i0 = blockIdx.x * 64;
    const int c0 = blockIdx.y * 128;

    const __bf16* qb = qT  + (size_t)b * NPTS * C4DIM;
    const __bf16* kb = kT  + (size_t)b * NPTS * C4DIM;
    const __bf16* vb = vin + (size_t)b * CDIM * NPTS;

    // DMA offsets (full K/V tiles staged by all 4 waves, swizzled groups)
    const int swz = (lane & 7) ^ ((lane >> 3) & 7);
    int koff[2], voff[4];
    #pragma unroll
    for (int s = 0; s < 2; s++) {
        int row = (2 * w + s) * 8 + (lane >> 3);
        koff[s] = row * 128 + swz * 16;
    }
    #pragma unroll
    for (int s = 0; s < 4; s++) {
        int row = (4 * w + s) * 8 + (lane >> 3);
        voff[s] = (c0 + row) * (NPTS * 2) + swz * 16;
    }

    // Q B-frags (swapped QK): lane l16 = i col, k = c = kc*32 + quad*8
    bf16x8 aq[2][2];
    #pragma unroll
    for (int rt = 0; rt < 2; rt++)
        #pragma unroll
        for (int kc = 0; kc < 2; kc++)
            aq[rt][kc] = *(const bf16x8*)&qb[(size_t)(i0 + 32 * r + 16 * rt + l16) * C4DIM
                                             + kc * 32 + quad * 8];

    bf16x8 vone;
    #pragma unroll
    for (int u = 0; u < 8; u++) vone[u] = (__bf16)1.0f;

    f32x4 O[2][8], lacc[2];
    #pragma unroll
    for (int rt = 0; rt < 2; rt++) {
        lacc[rt] = (f32x4)(0.f);
        #pragma unroll
        for (int tc = 0; tc < 8; tc++) O[rt][tc] = (f32x4)(0.f);
    }

    // prologue DMA tile 0 -> buf 0
    {
        const char* kbase = (const char*)kb;
        const char* vbase = (const char*)vb;
        #pragma unroll
        for (int s = 0; s < 2; s++) async_cp16(kbase + koff[s], Kb + (2 * w + s) * 1024);
        #pragma unroll
        for (int s = 0; s < 4; s++) async_cp16(vbase + voff[s], Vb + (4 * w + s) * 1024);
    }

    int p = 0;
    for (int j0 = 0; j0 < NPTS; j0 += 64, p ^= 1) {
        __syncthreads();   // drains DMA into buf p; buf p^1 reads done

        if (j0 + 64 < NPTS) {
            const char* kbase = (const char*)kb + (size_t)(j0 + 64) * (C4DIM * 2);
            const char* vbase = (const char*)vb + (size_t)(j0 + 64) * 2;
            unsigned char* Kd = Kb + (p ^ 1) * 8192;
            unsigned char* Vd = Vb + (p ^ 1) * 16384;
            #pragma unroll
            for (int s = 0; s < 2; s++) async_cp16(kbase + koff[s], Kd + (2 * w + s) * 1024);
            #pragma unroll
            for (int s = 0; s < 4; s++) async_cp16(vbase + voff[s], Vd + (4 * w + s) * 1024);
        }

        const unsigned char* K = Kb + p * 8192;
        const unsigned char* V = Vb + p * 16384;

        // ---- swapped QK: S[jt][it], lane holds S[i=16it+l16][j=16jt+4quad+r4]
        f32x4 S[2][2];
        #pragma unroll
        for (int jt = 0; jt < 2; jt++)
            #pragma unroll
            for (int it = 0; it < 2; it++) S[jt][it] = (f32x4)(0.f);
        #pragma unroll
        for (int kc = 0; kc < 2; kc++) {
            bf16x8 ka[2];    // A-frag: lane l16 = j row, k = c = kc*32+quad*8
            #pragma unroll
            for (int jt = 0; jt < 2; jt++) {
                int row = 32 * jh + 16 * jt + l16;
                int slot = (kc * 4 + quad) ^ (l16 & 7);
                ka[jt] = *(const bf16x8*)(K + row * 128 + slot * 16);
            }
            #pragma unroll
            for (int jt = 0; jt < 2; jt++)
                #pragma unroll
                for (int it = 0; it < 2; it++)
                    S[jt][it] = __builtin_amdgcn_mfma_f32_16x16x32_bf16(
                        ka[jt], aq[it][kc], S[jt][it], 0, 0, 0);
        }

        // ---- P = exp(s-32); pack + permlane-redistribute into k32 A-frags
        bf16x8 paf[2];
        #pragma unroll
        for (int it = 0; it < 2; it++) {
            float e[2][4];
            #pragma unroll
            for (int jt = 0; jt < 2; jt++)
                #pragma unroll
                for (int r4 = 0; r4 < 4; r4++)
                    e[jt][r4] = __builtin_amdgcn_exp2f(
                        __builtin_fmaf(S[jt][it][r4], 1.44269504088896340736f,
                                       -46.16624130844683f));
            union { unsigned u[4]; bf16x8 v; } fr;
            #pragma unroll
            for (int h = 0; h < 2; h++) {
                unsigned A = cvt_pk_bf16(e[0][2 * h], e[0][2 * h + 1]);  // jt0
                unsigned B = cvt_pk_bf16(e[1][2 * h], e[1][2 * h + 1]);  // jt1
                auto t2 = __builtin_amdgcn_permlane32_swap(A, B, false, false);
                auto xy = __builtin_amdgcn_permlane16_swap(t2[0], t2[1], false, false);
                fr.u[h]     = xy[0];   // k = 8*quad + 2h, +1
                fr.u[2 + h] = xy[1];   // k = 8*quad + 4 + 2h, +1
            }
            paf[it] = fr.v;
        }

        // ---- PV: k32 MFMAs, V as b128 B-frags (r9-verified pattern)
        __builtin_amdgcn_s_setprio(1);
        #pragma unroll
        for (int tc = 0; tc < 8; tc++) {
            int row = 16 * tc + l16;
            int slot = (jh * 4 + quad) ^ (l16 & 7);
            bf16x8 bv2 = *(const bf16x8*)(V + row * 128 + slot * 16);
            #pragma unroll
            for (int it = 0; it < 2; it++)
                O[it][tc] = __builtin_amdgcn_mfma_f32_16x16x32_bf16(
                    paf[it], bv2, O[it][tc], 0, 0, 0);
        }
        #pragma unroll
        for (int it = 0; it < 2; it++)
            lacc[it] = __builtin_amdgcn_mfma_f32_16x16x32_bf16(paf[it], vone,
                                                               lacc[it], 0, 0, 0);
        __builtin_amdgcn_s_setprio(0);
    }

    // ---- epilogue: combine j-half partials, gamma/l scale, transpose, +x
    __syncthreads();   // all K/V reads done; sm reusable
    const float g = gptr[0];
    float* Lp = (float*)(sm + 34816);

    if (jh == 1) {
        float* dst = (float*)(sm + (size_t)(r * 64 + lane) * 272);
        #pragma unroll
        for (int rt = 0; rt < 2; rt++)
            #pragma unroll
            for (int tc = 0; tc < 8; tc++)
                *(f32x4*)(dst + (rt * 8 + tc) * 4) = O[rt][tc];
        if (l16 == 0) {
            #pragma unroll
            for (int rt = 0; rt < 2; rt++)
                #pragma unroll
                for (int r4 = 0; r4 < 4; r4++)
                    Lp[32 * r + 16 * rt + 4 * quad + r4] = lacc[rt][r4];
        }
    }
    __syncthreads();

    float inv[2][4];
    if (jh == 0) {
        const float* src = (const float*)(sm + (size_t)(r * 64 + lane) * 272);
        #pragma unroll
        for (int rt = 0; rt < 2; rt++)
            #pragma unroll
            for (int tc = 0; tc < 8; tc++)
                O[rt][tc] += *(const f32x4*)(src + (rt * 8 + tc) * 4);
        #pragma unroll
        for (int rt = 0; rt < 2; rt++)
            #pragma unroll
            for (int r4 = 0; r4 < 4; r4++) {
                float ls = lacc[rt][r4] + Lp[32 * r + 16 * rt + 4 * quad + r4];
                inv[rt][r4] = g / ls;
            }
    }
    __syncthreads();   // partial reads done; OTa overlays same bytes

    auto OTa = (float (*)[68])sm;            // [128][68] fp32
    if (jh == 0) {
        #pragma unroll
        for (int rt = 0; rt < 2; rt++)
            #pragma unroll
            for (int tc = 0; tc < 8; tc++) {
                int c = 16 * tc + l16;
                float4 f;
                f.x = O[rt][tc][0] * inv[rt][0];
                f.y = O[rt][tc][1] * inv[rt][1];
                f.z = O[rt][tc][2] * inv[rt][2];
                f.w = O[rt][tc][3] * inv[rt][3];
                *(float4*)&OTa[c][32 * r + 16 * rt + 4 * quad] = f;
            }
    }
    __syncthreads();

    const float* xb = xin + (size_t)b * CDIM * NPTS;
    float*       ob = out + (size_t)b * CDIM * NPTS;
    #pragma unroll
    for (int s = 0; s < 8; s++) {
        int lin = t + 256 * s;            // 0..2047
        int c = lin >> 4, col = (lin & 15) * 4;
        size_t gi = (size_t)(c0 + c) * NPTS + i0 + col;
        float4 ov = *(const float4*)&OTa[c][col];
        float4 xv = *(const float4*)&xb[gi];
        float4 rr;
        rr.x = ov.x + xv.x; rr.y = ov.y + xv.y;
        rr.z = ov.z + xv.z; rr.w = ov.w + xv.w;
        *(float4*)&ob[gi] = rr;
    }
}

extern "C" void kernel_launch(void* const* d_in, const int* in_sizes, int n_in,
                              void* d_out, int out_size, void* d_ws, size_t ws_size,
                              hipStream_t stream) {
    const float* x     = (const float*)d_in[0];
    const float* Wq    = (const float*)d_in[1];
    const float* bq    = (const float*)d_in[2];
    const float* Wk    = (const float*)d_in[3];
    const float* bk    = (const float*)d_in[4];
    const float* Wv    = (const float*)d_in[5];
    const float* bv    = (const float*)d_in[6];
    const float* gamma = (const float*)d_in[7];

    const int B = 4;
    __bf16* qT  = (__bf16*)d_ws;                        // 2 MB
    __bf16* kT  = qT + (size_t)B * NPTS * C4DIM;        // 2 MB
    __bf16* v   = kT + (size_t)B * NPTS * C4DIM;        // 8 MB
    __bf16* wsz = v  + (size_t)B * CDIM * NPTS;         // 192 KB (swizzled bf16 W)

    wprep_kernel<<<96, 256, 0, stream>>>(Wq, Wk, Wv, wsz);

    proj_kernel<<<dim3(NPTS/32, B), 256, 0, stream>>>(
        x, bq, bk, bv, wsz, qT, kT, v);

    attn_kernel<<<dim3(NPTS/64, CDIM/128, B), 256, 0, stream>>>(
        qT, kT, v, x, gamma, (float*)d_out);
}

// Round 10
// 152.011 us; speedup vs baseline: 1.7575x; 1.0074x over previous
//
#include <hip/hip_runtime.h>

#define NPTS 4096
#define CDIM 256
#define C4DIM 64

typedef __bf16 bf16x8 __attribute__((ext_vector_type(8)));
typedef float  f32x4  __attribute__((ext_vector_type(4)));

__device__ __forceinline__ void async_cp16(const void* g, void* l) {
    __builtin_amdgcn_global_load_lds(
        (const __attribute__((address_space(1))) void*)g,
        (__attribute__((address_space(3))) void*)l, 16, 0, 0);
}

// v_cvt_pk_bf16_f32: D.lo16 = bf16(S0), D.hi16 = bf16(S1). No builtin on
// gfx950 (learn_hip m240) -> inline asm.
__device__ __forceinline__ unsigned cvt_pk_bf16(float lo, float hi) {
    unsigned r;
    asm("v_cvt_pk_bf16_f32 %0, %1, %2" : "=v"(r) : "v"(lo), "v"(hi));
    return r;
}

// ---------------------------------------------------------------------------
// W prep: fp32 -> bf16, rows [Wq(64) | Wk(64) | Wv(256)] = 384 x 256,
// with 16B-group swizzle within each 512B row: phys_group = g ^ (row & 7).
// (verbatim, HW-verified)
// ---------------------------------------------------------------------------
__global__ __launch_bounds__(256) void wprep_kernel(
    const float* __restrict__ Wq, const float* __restrict__ Wk,
    const float* __restrict__ Wv, __bf16* __restrict__ wsz)
{
    int idx = blockIdx.x * 256 + threadIdx.x;   // 0..24575
    int row = idx >> 6;                         // 0..383
    int l   = idx & 63;                         // float4 index within row
    const float* src;
    if (row < 64)       src = Wq + (size_t)row * CDIM;
    else if (row < 128) src = Wk + (size_t)(row - 64) * CDIM;
    else                src = Wv + (size_t)(row - 128) * CDIM;
    float4 f = *(const float4*)&src[l * 4];
    int g  = l >> 1;                 // logical 16B group 0..31
    int gp = g ^ (row & 7);          // physical slot
    union { __bf16 h[4]; uint2 u; } pk;
    pk.h[0] = (__bf16)f.x; pk.h[1] = (__bf16)f.y;
    pk.h[2] = (__bf16)f.z; pk.h[3] = (__bf16)f.w;
    *(uint2*)&wsz[(size_t)row * CDIM + gp * 8 + (l & 1) * 4] = pk.u;
}

// ---------------------------------------------------------------------------
// MFMA projection (round-7 version, verified): 32-n tiles,
// grid (NPTS/32, B), block 256; LDS 64KB -> 2 blocks/CU.
// ---------------------------------------------------------------------------
__global__ __launch_bounds__(256, 2) void proj_kernel(
    const float* __restrict__ x,
    const float* __restrict__ bq, const float* __restrict__ bk,
    const float* __restrict__ bv, const __bf16* __restrict__ wsz,
    __bf16* __restrict__ qT, __bf16* __restrict__ kT, __bf16* __restrict__ vo)
{
    __shared__ __align__(16) unsigned char sm[65536];
    auto Xs = (float (*)[33])sm;                 // [256][33] fp32, dies after A-build

    const int t    = threadIdx.x;
    const int w    = t >> 6;
    const int lane = t & 63;
    const int quad = lane >> 4;
    const int l16  = lane & 15;
    const int nq   = w >> 1;
    const int th   = w & 1;

    const int n0 = blockIdx.x * 32;
    const int b  = blockIdx.y;

    #pragma unroll
    for (int s = 0; s < 8; s++) {
        int lin = t + 256 * s;
        int c = lin >> 3, n4 = (lin & 7) * 4;
        *(float4*)&Xs[c][n4] =
            *(const float4*)&x[((size_t)b * CDIM + c) * NPTS + n0 + n4];
    }
    __syncthreads();

    bf16x8 af[8];
    #pragma unroll
    for (int kc = 0; kc < 8; kc++) {
        union { __bf16 h8[8]; bf16x8 v; } pk;
        #pragma unroll
        for (int u = 0; u < 8; u++)
            pk.h8[u] = (__bf16)Xs[kc * 32 + quad * 8 + u][16 * nq + l16];
        af[kc] = pk.v;
    }
    __syncthreads();

    const int lhalf = lane >> 5;
    const int rlow  = (2 * w + lhalf) & 7;
    const int slane = ((lane & 31) ^ rlow) * 8;

    #pragma unroll
    for (int s = 0; s < 8; s++)
        async_cp16(wsz + (size_t)(8 * s + 2 * w + lhalf) * CDIM + slane,
                   sm + (s * 4 + w) * 1024);

    f32x4 acc[6][2];
    #pragma unroll
    for (int ot = 0; ot < 6; ot++) {
        acc[ot][0] = (f32x4)(0.f);
        acc[ot][1] = (f32x4)(0.f);
    }

    #pragma unroll
    for (int ot = 0; ot < 6; ot++) {
        __syncthreads();
        if (ot < 5) {
            #pragma unroll
            for (int s = 0; s < 8; s++)
                async_cp16(wsz + (size_t)((ot + 1) * 64 + 8 * s + 2 * w + lhalf) * CDIM + slane,
                           sm + ((ot + 1) & 1) * 32768 + (s * 4 + w) * 1024);
        }
        const unsigned char* Wp = sm + (ot & 1) * 32768;
        #pragma unroll
        for (int kc = 0; kc < 8; kc++) {
            bf16x8 bw[2];
            #pragma unroll
            for (int tcl = 0; tcl < 2; tcl++)
                bw[tcl] = *(const bf16x8*)(Wp + (16 * (2 * th + tcl) + l16) * 512
                                              + (((kc * 4 + quad) ^ (l16 & 7)) << 4));
            #pragma unroll
            for (int tcl = 0; tcl < 2; tcl++)
                acc[ot][tcl] = __builtin_amdgcn_mfma_f32_16x16x32_bf16(
                    af[kc], bw[tcl], acc[ot][tcl], 0, 0, 0);
        }
    }

    {
        auto OT = (float (*)[68])sm;
        #pragma unroll
        for (int ot = 0; ot < 2; ot++) {
            __syncthreads();
            const float* bias = ot ? bk : bq;
            #pragma unroll
            for (int tcl = 0; tcl < 2; tcl++) {
                float bs = bias[16 * (2 * th + tcl) + l16];
                #pragma unroll
                for (int r4 = 0; r4 < 4; r4++)
                    OT[16 * nq + 4 * quad + r4][16 * (2 * th + tcl) + l16] =
                        acc[ot][tcl][r4] + bs;
            }
            __syncthreads();
            __bf16* outp = (ot == 0 ? qT : kT) + (size_t)b * NPTS * C4DIM;
            int n = t >> 3, op = (t & 7) * 8;
            f32x4 o0 = *(const f32x4*)&OT[n][op];
            f32x4 o1 = *(const f32x4*)&OT[n][op + 4];
            union { __bf16 h[8]; uint4 u; } pk;
            #pragma unroll
            for (int u2 = 0; u2 < 4; u2++) {
                pk.h[u2]     = (__bf16)o0[u2];
                pk.h[u2 + 4] = (__bf16)o1[u2];
            }
            *(uint4*)&outp[(size_t)(n0 + n) * C4DIM + op] = pk.u;
        }
    }
    {
        auto OTv = (float (*)[36])sm;
        #pragma unroll
        for (int ot = 2; ot < 6; ot++) {
            __syncthreads();
            #pragma unroll
            for (int tcl = 0; tcl < 2; tcl++) {
                float bs = bv[(ot - 2) * 64 + 16 * (2 * th + tcl) + l16];
                f32x4 v4 = acc[ot][tcl];
                v4[0] += bs; v4[1] += bs; v4[2] += bs; v4[3] += bs;
                *(f32x4*)&OTv[16 * (2 * th + tcl) + l16][16 * nq + 4 * quad] = v4;
            }
            __syncthreads();
            int cl = t >> 2, np = (t & 3) * 8;
            int ch = (ot - 2) * 64 + cl;
            f32x4 o0 = *(const f32x4*)&OTv[cl][np];
            f32x4 o1 = *(const f32x4*)&OTv[cl][np + 4];
            union { __bf16 h[8]; uint4 u; } pk;
            #pragma unroll
            for (int u2 = 0; u2 < 4; u2++) {
                pk.h[u2]     = (__bf16)o0[u2];
                pk.h[u2 + 4] = (__bf16)o1[u2];
            }
            *(uint4*)&vo[((size_t)b * CDIM + ch) * NPTS + n0 + np] = pk.u;
        }
    }
}

// ---------------------------------------------------------------------------
// MFMA flash attention, round 16 = r14 VERBATIM structure (verified 69.5us:
// in-register P via swapped QK + cvt_pk/permlane k32 A-frags, DMA-staged
// K/V double buffer, 1 barrier/iter, 65K bank conflicts) + setprio(1)
// extended to the QK read+MFMA cluster (T5 role-split: MFMA-phase waves
// preempt; exp/pack VALU phase runs at prio 0 so the other resident block's
// MFMA waves win the SIMD). Deferred-PV (r15) REVERTED: failed correctness
// (compiler-level race, m152-class); r11 measured its upside at ~1us anyway.
// ---------------------------------------------------------------------------
__global__ __launch_bounds__(256, 2) void attn_kernel(
    const __bf16* __restrict__ qT, const __bf16* __restrict__ kT,
    const __bf16* __restrict__ vin, const float* __restrict__ xin,
    const float* __restrict__ gptr, float* __restrict__ out)
{
    __shared__ __align__(16) unsigned char sm[49152];
    unsigned char* Kb = sm;                  // [2][64 rows][128 B] = 16384
    unsigned char* Vb = sm + 16384;          // [2][128 rows][128 B] = 32768
    // epilogue overlays (after barrier): Opart 128x272B, Lp at 34816

    const int t    = threadIdx.x;
    const int w    = t >> 6;
    const int lane = t & 63;
    const int quad = lane >> 4;
    const int l16  = lane & 15;
    const int r    = w >> 1;    // i row half
    const int jh   = w & 1;     // j half

    const int b  = blockIdx.z;
    const int i0 = blockIdx.x * 64;
    const int c0 = blockIdx.y * 128;

    const __bf16* qb = qT  + (size_t)b * NPTS * C4DIM;
    const __bf16* kb = kT  + (size_t)b * NPTS * C4DIM;
    const __bf16* vb = vin + (size_t)b * CDIM * NPTS;

    // DMA offsets (full K/V tiles staged by all 4 waves, swizzled groups)
    const int swz = (lane & 7) ^ ((lane >> 3) & 7);
    int koff[2], voff[4];
    #pragma unroll
    for (int s = 0; s < 2; s++) {
        int row = (2 * w + s) * 8 + (lane >> 3);
        koff[s] = row * 128 + swz * 16;
    }
    #pragma unroll
    for (int s = 0; s < 4; s++) {
        int row = (4 * w + s) * 8 + (lane >> 3);
        voff[s] = (c0 + row) * (NPTS * 2) + swz * 16;
    }

    // Q B-frags (swapped QK): lane l16 = i col, k = c = kc*32 + quad*8
    bf16x8 aq[2][2];
    #pragma unroll
    for (int rt = 0; rt < 2; rt++)
        #pragma unroll
        for (int kc = 0; kc < 2; kc++)
            aq[rt][kc] = *(const bf16x8*)&qb[(size_t)(i0 + 32 * r + 16 * rt + l16) * C4DIM
                                             + kc * 32 + quad * 8];

    bf16x8 vone;
    #pragma unroll
    for (int u = 0; u < 8; u++) vone[u] = (__bf16)1.0f;

    f32x4 O[2][8], lacc[2];
    #pragma unroll
    for (int rt = 0; rt < 2; rt++) {
        lacc[rt] = (f32x4)(0.f);
        #pragma unroll
        for (int tc = 0; tc < 8; tc++) O[rt][tc] = (f32x4)(0.f);
    }

    // prologue DMA tile 0 -> buf 0
    {
        const char* kbase = (const char*)kb;
        const char* vbase = (const char*)vb;
        #pragma unroll
        for (int s = 0; s < 2; s++) async_cp16(kbase + koff[s], Kb + (2 * w + s) * 1024);
        #pragma unroll
        for (int s = 0; s < 4; s++) async_cp16(vbase + voff[s], Vb + (4 * w + s) * 1024);
    }

    int p = 0;
    for (int j0 = 0; j0 < NPTS; j0 += 64, p ^= 1) {
        __syncthreads();   // drains DMA into buf p; buf p^1 reads done

        if (j0 + 64 < NPTS) {
            const char* kbase = (const char*)kb + (size_t)(j0 + 64) * (C4DIM * 2);
            const char* vbase = (const char*)vb + (size_t)(j0 + 64) * 2;
            unsigned char* Kd = Kb + (p ^ 1) * 8192;
            unsigned char* Vd = Vb + (p ^ 1) * 16384;
            #pragma unroll
            for (int s = 0; s < 2; s++) async_cp16(kbase + koff[s], Kd + (2 * w + s) * 1024);
            #pragma unroll
            for (int s = 0; s < 4; s++) async_cp16(vbase + voff[s], Vd + (4 * w + s) * 1024);
        }

        const unsigned char* K = Kb + p * 8192;
        const unsigned char* V = Vb + p * 16384;

        // ---- swapped QK: S[jt][it], lane holds S[i=16it+l16][j=16jt+4quad+r4]
        f32x4 S[2][2];
        #pragma unroll
        for (int jt = 0; jt < 2; jt++)
            #pragma unroll
            for (int it = 0; it < 2; it++) S[jt][it] = (f32x4)(0.f);
        __builtin_amdgcn_s_setprio(1);
        #pragma unroll
        for (int kc = 0; kc < 2; kc++) {
            bf16x8 ka[2];    // A-frag: lane l16 = j row, k = c = kc*32+quad*8
            #pragma unroll
            for (int jt = 0; jt < 2; jt++) {
                int row = 32 * jh + 16 * jt + l16;
                int slot = (kc * 4 + quad) ^ (l16 & 7);
                ka[jt] = *(const bf16x8*)(K + row * 128 + slot * 16);
            }
            #pragma unroll
            for (int jt = 0; jt < 2; jt++)
                #pragma unroll
                for (int it = 0; it < 2; it++)
                    S[jt][it] = __builtin_amdgcn_mfma_f32_16x16x32_bf16(
                        ka[jt], aq[it][kc], S[jt][it], 0, 0, 0);
        }
        __builtin_amdgcn_s_setprio(0);

        // ---- P = exp(s-32); pack + permlane-redistribute into k32 A-frags
        bf16x8 paf[2];
        #pragma unroll
        for (int it = 0; it < 2; it++) {
            float e[2][4];
            #pragma unroll
            for (int jt = 0; jt < 2; jt++)
                #pragma unroll
                for (int r4 = 0; r4 < 4; r4++)
                    e[jt][r4] = __builtin_amdgcn_exp2f(
                        __builtin_fmaf(S[jt][it][r4], 1.44269504088896340736f,
                                       -46.16624130844683f));
            union { unsigned u[4]; bf16x8 v; } fr;
            #pragma unroll
            for (int h = 0; h < 2; h++) {
                unsigned A = cvt_pk_bf16(e[0][2 * h], e[0][2 * h + 1]);  // jt0
                unsigned B = cvt_pk_bf16(e[1][2 * h], e[1][2 * h + 1]);  // jt1
                auto t2 = __builtin_amdgcn_permlane32_swap(A, B, false, false);
                auto xy = __builtin_amdgcn_permlane16_swap(t2[0], t2[1], false, false);
                fr.u[h]     = xy[0];   // k = 8*quad + 2h, +1
                fr.u[2 + h] = xy[1];   // k = 8*quad + 4 + 2h, +1
            }
            paf[it] = fr.v;
        }

        // ---- PV: k32 MFMAs, V as b128 B-frags (r9-verified pattern)
        __builtin_amdgcn_s_setprio(1);
        #pragma unroll
        for (int tc = 0; tc < 8; tc++) {
            int row = 16 * tc + l16;
            int slot = (jh * 4 + quad) ^ (l16 & 7);
            bf16x8 bv2 = *(const bf16x8*)(V + row * 128 + slot * 16);
            #pragma unroll
            for (int it = 0; it < 2; it++)
                O[it][tc] = __builtin_amdgcn_mfma_f32_16x16x32_bf16(
                    paf[it], bv2, O[it][tc], 0, 0, 0);
        }
        #pragma unroll
        for (int it = 0; it < 2; it++)
            lacc[it] = __builtin_amdgcn_mfma_f32_16x16x32_bf16(paf[it], vone,
                                                               lacc[it], 0, 0, 0);
        __builtin_amdgcn_s_setprio(0);
    }

    // ---- epilogue: combine j-half partials, gamma/l scale, transpose, +x
    __syncthreads();   // all K/V reads done; sm reusable
    const float g = gptr[0];
    float* Lp = (float*)(sm + 34816);

    if (jh == 1) {
        float* dst = (float*)(sm + (size_t)(r * 64 + lane) * 272);
        #pragma unroll
        for (int rt = 0; rt < 2; rt++)
            #pragma unroll
            for (int tc = 0; tc < 8; tc++)
                *(f32x4*)(dst + (rt * 8 + tc) * 4) = O[rt][tc];
        if (l16 == 0) {
            #pragma unroll
            for (int rt = 0; rt < 2; rt++)
                #pragma unroll
                for (int r4 = 0; r4 < 4; r4++)
                    Lp[32 * r + 16 * rt + 4 * quad + r4] = lacc[rt][r4];
        }
    }
    __syncthreads();

    float inv[2][4];
    if (jh == 0) {
        const float* src = (const float*)(sm + (size_t)(r * 64 + lane) * 272);
        #pragma unroll
        for (int rt = 0; rt < 2; rt++)
            #pragma unroll
            for (int tc = 0; tc < 8; tc++)
                O[rt][tc] += *(const f32x4*)(src + (rt * 8 + tc) * 4);
        #pragma unroll
        for (int rt = 0; rt < 2; rt++)
            #pragma unroll
            for (int r4 = 0; r4 < 4; r4++) {
                float ls = lacc[rt][r4] + Lp[32 * r + 16 * rt + 4 * quad + r4];
                inv[rt][r4] = g / ls;
            }
    }
    __syncthreads();   // partial reads done; OTa overlays same bytes

    auto OTa = (float (*)[68])sm;            // [128][68] fp32
    if (jh == 0) {
        #pragma unroll
        for (int rt = 0; rt < 2; rt++)
            #pragma unroll
            for (int tc = 0; tc < 8; tc++) {
                int c = 16 * tc + l16;
                float4 f;
                f.x = O[rt][tc][0] * inv[rt][0];
                f.y = O[rt][tc][1] * inv[rt][1];
                f.z = O[rt][tc][2] * inv[rt][2];
                f.w = O[rt][tc][3] * inv[rt][3];
                *(float4*)&OTa[c][32 * r + 16 * rt + 4 * quad] = f;
            }
    }
    __syncthreads();

    const float* xb = xin + (size_t)b * CDIM * NPTS;
    float*       ob = out + (size_t)b * CDIM * NPTS;
    #pragma unroll
    for (int s = 0; s < 8; s++) {
        int lin = t + 256 * s;            // 0..2047
        int c = lin >> 4, col = (lin & 15) * 4;
        size_t gi = (size_t)(c0 + c) * NPTS + i0 + col;
        float4 ov = *(const float4*)&OTa[c][col];
        float4 xv = *(const float4*)&xb[gi];
        float4 rr;
        rr.x = ov.x + xv.x; rr.y = ov.y + xv.y;
        rr.z = ov.z + xv.z; rr.w = ov.w + xv.w;
        *(float4*)&ob[gi] = rr;
    }
}

extern "C" void kernel_launch(void* const* d_in, const int* in_sizes, int n_in,
                              void* d_out, int out_size, void* d_ws, size_t ws_size,
                              hipStream_t stream) {
    const float* x     = (const float*)d_in[0];
    const float* Wq    = (const float*)d_in[1];
    const float* bq    = (const float*)d_in[2];
    const float* Wk    = (const float*)d_in[3];
    const float* bk    = (const float*)d_in[4];
    const float* Wv    = (const float*)d_in[5];
    const float* bv    = (const float*)d_in[6];
    const float* gamma = (const float*)d_in[7];

    const int B = 4;
    __bf16* qT  = (__bf16*)d_ws;                        // 2 MB
    __bf16* kT  = qT + (size_t)B * NPTS * C4DIM;        // 2 MB
    __bf16* v   = kT + (size_t)B * NPTS * C4DIM;        // 8 MB
    __bf16* wsz = v  + (size_t)B * CDIM * NPTS;         // 192 KB (swizzled bf16 W)

    wprep_kernel<<<96, 256, 0, stream>>>(Wq, Wk, Wv, wsz);

    proj_kernel<<<dim3(NPTS/32, B), 256, 0, stream>>>(
        x, bq, bk, bv, wsz, qT, kT, v);

    attn_kernel<<<dim3(NPTS/64, CDIM/128, B), 256, 0, stream>>>(
        qT, kT, v, x, gamma, (float*)d_out);
}

// Round 11
// 151.574 us; speedup vs baseline: 1.7626x; 1.0029x over previous
//
#include <hip/hip_runtime.h>

#define NPTS 4096
#define CDIM 256
#define C4DIM 64

typedef __bf16 bf16x8 __attribute__((ext_vector_type(8)));
typedef float  f32x4  __attribute__((ext_vector_type(4)));

__device__ __forceinline__ void async_cp16(const void* g, void* l) {
    __builtin_amdgcn_global_load_lds(
        (const __attribute__((address_space(1))) void*)g,
        (__attribute__((address_space(3))) void*)l, 16, 0, 0);
}

// v_cvt_pk_bf16_f32: D.lo16 = bf16(S0), D.hi16 = bf16(S1). No builtin on
// gfx950 (learn_hip m240) -> inline asm.
__device__ __forceinline__ unsigned cvt_pk_bf16(float lo, float hi) {
    unsigned r;
    asm("v_cvt_pk_bf16_f32 %0, %1, %2" : "=v"(r) : "v"(lo), "v"(hi));
    return r;
}

// ---------------------------------------------------------------------------
// W prep: fp32 -> bf16, rows [Wq(64) | Wk(64) | Wv(256)] = 384 x 256,
// with 16B-group swizzle within each 512B row: phys_group = g ^ (row & 7).
// (verbatim, HW-verified)
// ---------------------------------------------------------------------------
__global__ __launch_bounds__(256) void wprep_kernel(
    const float* __restrict__ Wq, const float* __restrict__ Wk,
    const float* __restrict__ Wv, __bf16* __restrict__ wsz)
{
    int idx = blockIdx.x * 256 + threadIdx.x;   // 0..24575
    int row = idx >> 6;                         // 0..383
    int l   = idx & 63;                         // float4 index within row
    const float* src;
    if (row < 64)       src = Wq + (size_t)row * CDIM;
    else if (row < 128) src = Wk + (size_t)(row - 64) * CDIM;
    else                src = Wv + (size_t)(row - 128) * CDIM;
    float4 f = *(const float4*)&src[l * 4];
    int g  = l >> 1;                 // logical 16B group 0..31
    int gp = g ^ (row & 7);          // physical slot
    union { __bf16 h[4]; uint2 u; } pk;
    pk.h[0] = (__bf16)f.x; pk.h[1] = (__bf16)f.y;
    pk.h[2] = (__bf16)f.z; pk.h[3] = (__bf16)f.w;
    *(uint2*)&wsz[(size_t)row * CDIM + gp * 8 + (l & 1) * 4] = pk.u;
}

// ---------------------------------------------------------------------------
// MFMA projection (round-7 version, verified): 32-n tiles,
// grid (NPTS/32, B), block 256; LDS 64KB -> 2 blocks/CU.
// ---------------------------------------------------------------------------
__global__ __launch_bounds__(256, 2) void proj_kernel(
    const float* __restrict__ x,
    const float* __restrict__ bq, const float* __restrict__ bk,
    const float* __restrict__ bv, const __bf16* __restrict__ wsz,
    __bf16* __restrict__ qT, __bf16* __restrict__ kT, __bf16* __restrict__ vo)
{
    __shared__ __align__(16) unsigned char sm[65536];
    auto Xs = (float (*)[33])sm;                 // [256][33] fp32, dies after A-build

    const int t    = threadIdx.x;
    const int w    = t >> 6;
    const int lane = t & 63;
    const int quad = lane >> 4;
    const int l16  = lane & 15;
    const int nq   = w >> 1;
    const int th   = w & 1;

    const int n0 = blockIdx.x * 32;
    const int b  = blockIdx.y;

    #pragma unroll
    for (int s = 0; s < 8; s++) {
        int lin = t + 256 * s;
        int c = lin >> 3, n4 = (lin & 7) * 4;
        *(float4*)&Xs[c][n4] =
            *(const float4*)&x[((size_t)b * CDIM + c) * NPTS + n0 + n4];
    }
    __syncthreads();

    bf16x8 af[8];
    #pragma unroll
    for (int kc = 0; kc < 8; kc++) {
        union { __bf16 h8[8]; bf16x8 v; } pk;
        #pragma unroll
        for (int u = 0; u < 8; u++)
            pk.h8[u] = (__bf16)Xs[kc * 32 + quad * 8 + u][16 * nq + l16];
        af[kc] = pk.v;
    }
    __syncthreads();

    const int lhalf = lane >> 5;
    const int rlow  = (2 * w + lhalf) & 7;
    const int slane = ((lane & 31) ^ rlow) * 8;

    #pragma unroll
    for (int s = 0; s < 8; s++)
        async_cp16(wsz + (size_t)(8 * s + 2 * w + lhalf) * CDIM + slane,
                   sm + (s * 4 + w) * 1024);

    f32x4 acc[6][2];
    #pragma unroll
    for (int ot = 0; ot < 6; ot++) {
        acc[ot][0] = (f32x4)(0.f);
        acc[ot][1] = (f32x4)(0.f);
    }

    #pragma unroll
    for (int ot = 0; ot < 6; ot++) {
        __syncthreads();
        if (ot < 5) {
            #pragma unroll
            for (int s = 0; s < 8; s++)
                async_cp16(wsz + (size_t)((ot + 1) * 64 + 8 * s + 2 * w + lhalf) * CDIM + slane,
                           sm + ((ot + 1) & 1) * 32768 + (s * 4 + w) * 1024);
        }
        const unsigned char* Wp = sm + (ot & 1) * 32768;
        #pragma unroll
        for (int kc = 0; kc < 8; kc++) {
            bf16x8 bw[2];
            #pragma unroll
            for (int tcl = 0; tcl < 2; tcl++)
                bw[tcl] = *(const bf16x8*)(Wp + (16 * (2 * th + tcl) + l16) * 512
                                              + (((kc * 4 + quad) ^ (l16 & 7)) << 4));
            #pragma unroll
            for (int tcl = 0; tcl < 2; tcl++)
                acc[ot][tcl] = __builtin_amdgcn_mfma_f32_16x16x32_bf16(
                    af[kc], bw[tcl], acc[ot][tcl], 0, 0, 0);
        }
    }

    {
        auto OT = (float (*)[68])sm;
        #pragma unroll
        for (int ot = 0; ot < 2; ot++) {
            __syncthreads();
            const float* bias = ot ? bk : bq;
            #pragma unroll
            for (int tcl = 0; tcl < 2; tcl++) {
                float bs = bias[16 * (2 * th + tcl) + l16];
                #pragma unroll
                for (int r4 = 0; r4 < 4; r4++)
                    OT[16 * nq + 4 * quad + r4][16 * (2 * th + tcl) + l16] =
                        acc[ot][tcl][r4] + bs;
            }
            __syncthreads();
            __bf16* outp = (ot == 0 ? qT : kT) + (size_t)b * NPTS * C4DIM;
            int n = t >> 3, op = (t & 7) * 8;
            f32x4 o0 = *(const f32x4*)&OT[n][op];
            f32x4 o1 = *(const f32x4*)&OT[n][op + 4];
            union { __bf16 h[8]; uint4 u; } pk;
            #pragma unroll
            for (int u2 = 0; u2 < 4; u2++) {
                pk.h[u2]     = (__bf16)o0[u2];
                pk.h[u2 + 4] = (__bf16)o1[u2];
            }
            *(uint4*)&outp[(size_t)(n0 + n) * C4DIM + op] = pk.u;
        }
    }
    {
        auto OTv = (float (*)[36])sm;
        #pragma unroll
        for (int ot = 2; ot < 6; ot++) {
            __syncthreads();
            #pragma unroll
            for (int tcl = 0; tcl < 2; tcl++) {
                float bs = bv[(ot - 2) * 64 + 16 * (2 * th + tcl) + l16];
                f32x4 v4 = acc[ot][tcl];
                v4[0] += bs; v4[1] += bs; v4[2] += bs; v4[3] += bs;
                *(f32x4*)&OTv[16 * (2 * th + tcl) + l16][16 * nq + 4 * quad] = v4;
            }
            __syncthreads();
            int cl = t >> 2, np = (t & 3) * 8;
            int ch = (ot - 2) * 64 + cl;
            f32x4 o0 = *(const f32x4*)&OTv[cl][np];
            f32x4 o1 = *(const f32x4*)&OTv[cl][np + 4];
            union { __bf16 h[8]; uint4 u; } pk;
            #pragma unroll
            for (int u2 = 0; u2 < 4; u2++) {
                pk.h[u2]     = (__bf16)o0[u2];
                pk.h[u2 + 4] = (__bf16)o1[u2];
            }
            *(uint4*)&vo[((size_t)b * CDIM + ch) * NPTS + n0 + np] = pk.u;
        }
    }
}

// ---------------------------------------------------------------------------
// MFMA flash attention, round 17 = r14 verbatim (verified 69.5us: in-register
// P via swapped QK + cvt_pk/permlane k32 A-frags, DMA double buffer, 65K
// conflicts, PV-only setprio) + V-read hoist: all 8 V ds_read_b128 issue
// right after the K-frag reads, BEFORE the QK MFMAs, so V-read latency hides
// under QK + exp/pack (~300 cyc of matrix+VALU work) instead of bursting
// with exposed latency inside the PV loop. Same reads / same barrier period /
// same wave -> zero semantic change. QK setprio (r16) reverted: measured
// -4us (prioritizing lgkmcnt-stalling waves starves the other block's PV).
// ---------------------------------------------------------------------------
__global__ __launch_bounds__(256, 2) void attn_kernel(
    const __bf16* __restrict__ qT, const __bf16* __restrict__ kT,
    const __bf16* __restrict__ vin, const float* __restrict__ xin,
    const float* __restrict__ gptr, float* __restrict__ out)
{
    __shared__ __align__(16) unsigned char sm[49152];
    unsigned char* Kb = sm;                  // [2][64 rows][128 B] = 16384
    unsigned char* Vb = sm + 16384;          // [2][128 rows][128 B] = 32768
    // epilogue overlays (after barrier): Opart 128x272B, Lp at 34816

    const int t    = threadIdx.x;
    const int w    = t >> 6;
    const int lane = t & 63;
    const int quad = lane >> 4;
    const int l16  = lane & 15;
    const int r    = w >> 1;    // i row half
    const int jh   = w & 1;     // j half

    const int b  = blockIdx.z;
    const int i0 = blockIdx.x * 64;
    const int c0 = blockIdx.y * 128;

    const __bf16* qb = qT  + (size_t)b * NPTS * C4DIM;
    const __bf16* kb = kT  + (size_t)b * NPTS * C4DIM;
    const __bf16* vb = vin + (size_t)b * CDIM * NPTS;

    // DMA offsets (full K/V tiles staged by all 4 waves, swizzled groups)
    const int swz = (lane & 7) ^ ((lane >> 3) & 7);
    int koff[2], voff[4];
    #pragma unroll
    for (int s = 0; s < 2; s++) {
        int row = (2 * w + s) * 8 + (lane >> 3);
        koff[s] = row * 128 + swz * 16;
    }
    #pragma unroll
    for (int s = 0; s < 4; s++) {
        int row = (4 * w + s) * 8 + (lane >> 3);
        voff[s] = (c0 + row) * (NPTS * 2) + swz * 16;
    }

    // Q B-frags (swapped QK): lane l16 = i col, k = c = kc*32 + quad*8
    bf16x8 aq[2][2];
    #pragma unroll
    for (int rt = 0; rt < 2; rt++)
        #pragma unroll
        for (int kc = 0; kc < 2; kc++)
            aq[rt][kc] = *(const bf16x8*)&qb[(size_t)(i0 + 32 * r + 16 * rt + l16) * C4DIM
                                             + kc * 32 + quad * 8];

    bf16x8 vone;
    #pragma unroll
    for (int u = 0; u < 8; u++) vone[u] = (__bf16)1.0f;

    f32x4 O[2][8], lacc[2];
    #pragma unroll
    for (int rt = 0; rt < 2; rt++) {
        lacc[rt] = (f32x4)(0.f);
        #pragma unroll
        for (int tc = 0; tc < 8; tc++) O[rt][tc] = (f32x4)(0.f);
    }

    // prologue DMA tile 0 -> buf 0
    {
        const char* kbase = (const char*)kb;
        const char* vbase = (const char*)vb;
        #pragma unroll
        for (int s = 0; s < 2; s++) async_cp16(kbase + koff[s], Kb + (2 * w + s) * 1024);
        #pragma unroll
        for (int s = 0; s < 4; s++) async_cp16(vbase + voff[s], Vb + (4 * w + s) * 1024);
    }

    int p = 0;
    for (int j0 = 0; j0 < NPTS; j0 += 64, p ^= 1) {
        __syncthreads();   // drains DMA into buf p; buf p^1 reads done

        if (j0 + 64 < NPTS) {
            const char* kbase = (const char*)kb + (size_t)(j0 + 64) * (C4DIM * 2);
            const char* vbase = (const char*)vb + (size_t)(j0 + 64) * 2;
            unsigned char* Kd = Kb + (p ^ 1) * 8192;
            unsigned char* Vd = Vb + (p ^ 1) * 16384;
            #pragma unroll
            for (int s = 0; s < 2; s++) async_cp16(kbase + koff[s], Kd + (2 * w + s) * 1024);
            #pragma unroll
            for (int s = 0; s < 4; s++) async_cp16(vbase + voff[s], Vd + (4 * w + s) * 1024);
        }

        const unsigned char* K = Kb + p * 8192;
        const unsigned char* V = Vb + p * 16384;

        // ---- issue ALL LDS reads for this tile up front: 4 K + 8 V b128.
        // V reads have no dependency on QK; hoisting hides their latency
        // under the QK MFMAs and exp/pack VALU phase.
        bf16x8 ka[2][2];   // [kc][jt]
        #pragma unroll
        for (int kc = 0; kc < 2; kc++)
            #pragma unroll
            for (int jt = 0; jt < 2; jt++) {
                int row = 32 * jh + 16 * jt + l16;
                int slot = (kc * 4 + quad) ^ (l16 & 7);
                ka[kc][jt] = *(const bf16x8*)(K + row * 128 + slot * 16);
            }
        bf16x8 vv[8];
        #pragma unroll
        for (int tc = 0; tc < 8; tc++) {
            int row = 16 * tc + l16;
            int slot = (jh * 4 + quad) ^ (l16 & 7);
            vv[tc] = *(const bf16x8*)(V + row * 128 + slot * 16);
        }

        // ---- swapped QK: S[jt][it], lane holds S[i=16it+l16][j=16jt+4quad+r4]
        f32x4 S[2][2];
        #pragma unroll
        for (int jt = 0; jt < 2; jt++)
            #pragma unroll
            for (int it = 0; it < 2; it++) S[jt][it] = (f32x4)(0.f);
        #pragma unroll
        for (int kc = 0; kc < 2; kc++)
            #pragma unroll
            for (int jt = 0; jt < 2; jt++)
                #pragma unroll
                for (int it = 0; it < 2; it++)
                    S[jt][it] = __builtin_amdgcn_mfma_f32_16x16x32_bf16(
                        ka[kc][jt], aq[it][kc], S[jt][it], 0, 0, 0);

        // ---- P = exp(s-32); pack + permlane-redistribute into k32 A-frags
        bf16x8 paf[2];
        #pragma unroll
        for (int it = 0; it < 2; it++) {
            float e[2][4];
            #pragma unroll
            for (int jt = 0; jt < 2; jt++)
                #pragma unroll
                for (int r4 = 0; r4 < 4; r4++)
                    e[jt][r4] = __builtin_amdgcn_exp2f(
                        __builtin_fmaf(S[jt][it][r4], 1.44269504088896340736f,
                                       -46.16624130844683f));
            union { unsigned u[4]; bf16x8 v; } fr;
            #pragma unroll
            for (int h = 0; h < 2; h++) {
                unsigned A = cvt_pk_bf16(e[0][2 * h], e[0][2 * h + 1]);  // jt0
                unsigned B = cvt_pk_bf16(e[1][2 * h], e[1][2 * h + 1]);  // jt1
                auto t2 = __builtin_amdgcn_permlane32_swap(A, B, false, false);
                auto xy = __builtin_amdgcn_permlane16_swap(t2[0], t2[1], false, false);
                fr.u[h]     = xy[0];   // k = 8*quad + 2h, +1
                fr.u[2 + h] = xy[1];   // k = 8*quad + 4 + 2h, +1
            }
            paf[it] = fr.v;
        }

        // ---- PV: k32 MFMAs from preloaded vv (pure-register cluster)
        __builtin_amdgcn_s_setprio(1);
        #pragma unroll
        for (int tc = 0; tc < 8; tc++)
            #pragma unroll
            for (int it = 0; it < 2; it++)
                O[it][tc] = __builtin_amdgcn_mfma_f32_16x16x32_bf16(
                    paf[it], vv[tc], O[it][tc], 0, 0, 0);
        #pragma unroll
        for (int it = 0; it < 2; it++)
            lacc[it] = __builtin_amdgcn_mfma_f32_16x16x32_bf16(paf[it], vone,
                                                               lacc[it], 0, 0, 0);
        __builtin_amdgcn_s_setprio(0);
    }

    // ---- epilogue: combine j-half partials, gamma/l scale, transpose, +x
    __syncthreads();   // all K/V reads done; sm reusable
    const float g = gptr[0];
    float* Lp = (float*)(sm + 34816);

    if (jh == 1) {
        float* dst = (float*)(sm + (size_t)(r * 64 + lane) * 272);
        #pragma unroll
        for (int rt = 0; rt < 2; rt++)
            #pragma unroll
            for (int tc = 0; tc < 8; tc++)
                *(f32x4*)(dst + (rt * 8 + tc) * 4) = O[rt][tc];
        if (l16 == 0) {
            #pragma unroll
            for (int rt = 0; rt < 2; rt++)
                #pragma unroll
                for (int r4 = 0; r4 < 4; r4++)
                    Lp[32 * r + 16 * rt + 4 * quad + r4] = lacc[rt][r4];
        }
    }
    __syncthreads();

    float inv[2][4];
    if (jh == 0) {
        const float* src = (const float*)(sm + (size_t)(r * 64 + lane) * 272);
        #pragma unroll
        for (int rt = 0; rt < 2; rt++)
            #pragma unroll
            for (int tc = 0; tc < 8; tc++)
                O[rt][tc] += *(const f32x4*)(src + (rt * 8 + tc) * 4);
        #pragma unroll
        for (int rt = 0; rt < 2; rt++)
            #pragma unroll
            for (int r4 = 0; r4 < 4; r4++) {
                float ls = lacc[rt][r4] + Lp[32 * r + 16 * rt + 4 * quad + r4];
                inv[rt][r4] = g / ls;
            }
    }
    __syncthreads();   // partial reads done; OTa overlays same bytes

    auto OTa = (float (*)[68])sm;            // [128][68] fp32
    if (jh == 0) {
        #pragma unroll
        for (int rt = 0; rt < 2; rt++)
            #pragma unroll
            for (int tc = 0; tc < 8; tc++) {
                int c = 16 * tc + l16;
                float4 f;
                f.x = O[rt][tc][0] * inv[rt][0];
                f.y = O[rt][tc][1] * inv[rt][1];
                f.z = O[rt][tc][2] * inv[rt][2];
                f.w = O[rt][tc][3] * inv[rt][3];
                *(float4*)&OTa[c][32 * r + 16 * rt + 4 * quad] = f;
            }
    }
    __syncthreads();

    const float* xb = xin + (size_t)b * CDIM * NPTS;
    float*       ob = out + (size_t)b * CDIM * NPTS;
    #pragma unroll
    for (int s = 0; s < 8; s++) {
        int lin = t + 256 * s;            // 0..2047
        int c = lin >> 4, col = (lin & 15) * 4;
        size_t gi = (size_t)(c0 + c) * NPTS + i0 + col;
        float4 ov = *(const float4*)&OTa[c][col];
        float4 xv = *(const float4*)&xb[gi];
        float4 rr;
        rr.x = ov.x + xv.x; rr.y = ov.y + xv.y;
        rr.z = ov.z + xv.z; rr.w = ov.w + xv.w;
        *(float4*)&ob[gi] = rr;
    }
}

extern "C" void kernel_launch(void* const* d_in, const int* in_sizes, int n_in,
                              void* d_out, int out_size, void* d_ws, size_t ws_size,
                              hipStream_t stream) {
    const float* x     = (const float*)d_in[0];
    const float* Wq    = (const float*)d_in[1];
    const float* bq    = (const float*)d_in[2];
    const float* Wk    = (const float*)d_in[3];
    const float* bk    = (const float*)d_in[4];
    const float* Wv    = (const float*)d_in[5];
    const float* bv    = (const float*)d_in[6];
    const float* gamma = (const float*)d_in[7];

    const int B = 4;
    __bf16* qT  = (__bf16*)d_ws;                        // 2 MB
    __bf16* kT  = qT + (size_t)B * NPTS * C4DIM;        // 2 MB
    __bf16* v   = kT + (size_t)B * NPTS * C4DIM;        // 8 MB
    __bf16* wsz = v  + (size_t)B * CDIM * NPTS;         // 192 KB (swizzled bf16 W)

    wprep_kernel<<<96, 256, 0, stream>>>(Wq, Wk, Wv, wsz);

    proj_kernel<<<dim3(NPTS/32, B), 256, 0, stream>>>(
        x, bq, bk, bv, wsz, qT, kT, v);

    attn_kernel<<<dim3(NPTS/64, CDIM/128, B), 256, 0, stream>>>(
        qT, kT, v, x, gamma, (float*)d_out);
}

// Round 12
// 149.915 us; speedup vs baseline: 1.7821x; 1.0111x over previous
//
#include <hip/hip_runtime.h>

#define NPTS 4096
#define CDIM 256
#define C4DIM 64

typedef __bf16 bf16x8 __attribute__((ext_vector_type(8)));
typedef float  f32x4  __attribute__((ext_vector_type(4)));

__device__ __forceinline__ void async_cp16(const void* g, void* l) {
    __builtin_amdgcn_global_load_lds(
        (const __attribute__((address_space(1))) void*)g,
        (__attribute__((address_space(3))) void*)l, 16, 0, 0);
}

// v_cvt_pk_bf16_f32: D.lo16 = bf16(S0), D.hi16 = bf16(S1). No builtin on
// gfx950 (learn_hip m240) -> inline asm.
__device__ __forceinline__ unsigned cvt_pk_bf16(float lo, float hi) {
    unsigned r;
    asm("v_cvt_pk_bf16_f32 %0, %1, %2" : "=v"(r) : "v"(lo), "v"(hi));
    return r;
}

// ---------------------------------------------------------------------------
// W prep: fp32 -> bf16, rows [Wq(64) | Wk(64) | Wv(256)] = 384 x 256,
// with 16B-group swizzle within each 512B row: phys_group = g ^ (row & 7).
// (verbatim, HW-verified)
// ---------------------------------------------------------------------------
__global__ __launch_bounds__(256) void wprep_kernel(
    const float* __restrict__ Wq, const float* __restrict__ Wk,
    const float* __restrict__ Wv, __bf16* __restrict__ wsz)
{
    int idx = blockIdx.x * 256 + threadIdx.x;   // 0..24575
    int row = idx >> 6;                         // 0..383
    int l   = idx & 63;                         // float4 index within row
    const float* src;
    if (row < 64)       src = Wq + (size_t)row * CDIM;
    else if (row < 128) src = Wk + (size_t)(row - 64) * CDIM;
    else                src = Wv + (size_t)(row - 128) * CDIM;
    float4 f = *(const float4*)&src[l * 4];
    int g  = l >> 1;                 // logical 16B group 0..31
    int gp = g ^ (row & 7);          // physical slot
    union { __bf16 h[4]; uint2 u; } pk;
    pk.h[0] = (__bf16)f.x; pk.h[1] = (__bf16)f.y;
    pk.h[2] = (__bf16)f.z; pk.h[3] = (__bf16)f.w;
    *(uint2*)&wsz[(size_t)row * CDIM + gp * 8 + (l & 1) * 4] = pk.u;
}

// ---------------------------------------------------------------------------
// MFMA projection (round-7 version, verified): 32-n tiles,
// grid (NPTS/32, B), block 256; LDS 64KB -> 2 blocks/CU.
// ---------------------------------------------------------------------------
__global__ __launch_bounds__(256, 2) void proj_kernel(
    const float* __restrict__ x,
    const float* __restrict__ bq, const float* __restrict__ bk,
    const float* __restrict__ bv, const __bf16* __restrict__ wsz,
    __bf16* __restrict__ qT, __bf16* __restrict__ kT, __bf16* __restrict__ vo)
{
    __shared__ __align__(16) unsigned char sm[65536];
    auto Xs = (float (*)[33])sm;                 // [256][33] fp32, dies after A-build

    const int t    = threadIdx.x;
    const int w    = t >> 6;
    const int lane = t & 63;
    const int quad = lane >> 4;
    const int l16  = lane & 15;
    const int nq   = w >> 1;
    const int th   = w & 1;

    const int n0 = blockIdx.x * 32;
    const int b  = blockIdx.y;

    #pragma unroll
    for (int s = 0; s < 8; s++) {
        int lin = t + 256 * s;
        int c = lin >> 3, n4 = (lin & 7) * 4;
        *(float4*)&Xs[c][n4] =
            *(const float4*)&x[((size_t)b * CDIM + c) * NPTS + n0 + n4];
    }
    __syncthreads();

    bf16x8 af[8];
    #pragma unroll
    for (int kc = 0; kc < 8; kc++) {
        union { __bf16 h8[8]; bf16x8 v; } pk;
        #pragma unroll
        for (int u = 0; u < 8; u++)
            pk.h8[u] = (__bf16)Xs[kc * 32 + quad * 8 + u][16 * nq + l16];
        af[kc] = pk.v;
    }
    __syncthreads();

    const int lhalf = lane >> 5;
    const int rlow  = (2 * w + lhalf) & 7;
    const int slane = ((lane & 31) ^ rlow) * 8;

    #pragma unroll
    for (int s = 0; s < 8; s++)
        async_cp16(wsz + (size_t)(8 * s + 2 * w + lhalf) * CDIM + slane,
                   sm + (s * 4 + w) * 1024);

    f32x4 acc[6][2];
    #pragma unroll
    for (int ot = 0; ot < 6; ot++) {
        acc[ot][0] = (f32x4)(0.f);
        acc[ot][1] = (f32x4)(0.f);
    }

    #pragma unroll
    for (int ot = 0; ot < 6; ot++) {
        __syncthreads();
        if (ot < 5) {
            #pragma unroll
            for (int s = 0; s < 8; s++)
                async_cp16(wsz + (size_t)((ot + 1) * 64 + 8 * s + 2 * w + lhalf) * CDIM + slane,
                           sm + ((ot + 1) & 1) * 32768 + (s * 4 + w) * 1024);
        }
        const unsigned char* Wp = sm + (ot & 1) * 32768;
        #pragma unroll
        for (int kc = 0; kc < 8; kc++) {
            bf16x8 bw[2];
            #pragma unroll
            for (int tcl = 0; tcl < 2; tcl++)
                bw[tcl] = *(const bf16x8*)(Wp + (16 * (2 * th + tcl) + l16) * 512
                                              + (((kc * 4 + quad) ^ (l16 & 7)) << 4));
            #pragma unroll
            for (int tcl = 0; tcl < 2; tcl++)
                acc[ot][tcl] = __builtin_amdgcn_mfma_f32_16x16x32_bf16(
                    af[kc], bw[tcl], acc[ot][tcl], 0, 0, 0);
        }
    }

    {
        auto OT = (float (*)[68])sm;
        #pragma unroll
        for (int ot = 0; ot < 2; ot++) {
            __syncthreads();
            const float* bias = ot ? bk : bq;
            #pragma unroll
            for (int tcl = 0; tcl < 2; tcl++) {
                float bs = bias[16 * (2 * th + tcl) + l16];
                #pragma unroll
                for (int r4 = 0; r4 < 4; r4++)
                    OT[16 * nq + 4 * quad + r4][16 * (2 * th + tcl) + l16] =
                        acc[ot][tcl][r4] + bs;
            }
            __syncthreads();
            __bf16* outp = (ot == 0 ? qT : kT) + (size_t)b * NPTS * C4DIM;
            int n = t >> 3, op = (t & 7) * 8;
            f32x4 o0 = *(const f32x4*)&OT[n][op];
            f32x4 o1 = *(const f32x4*)&OT[n][op + 4];
            union { __bf16 h[8]; uint4 u; } pk;
            #pragma unroll
            for (int u2 = 0; u2 < 4; u2++) {
                pk.h[u2]     = (__bf16)o0[u2];
                pk.h[u2 + 4] = (__bf16)o1[u2];
            }
            *(uint4*)&outp[(size_t)(n0 + n) * C4DIM + op] = pk.u;
        }
    }
    {
        auto OTv = (float (*)[36])sm;
        #pragma unroll
        for (int ot = 2; ot < 6; ot++) {
            __syncthreads();
            #pragma unroll
            for (int tcl = 0; tcl < 2; tcl++) {
                float bs = bv[(ot - 2) * 64 + 16 * (2 * th + tcl) + l16];
                f32x4 v4 = acc[ot][tcl];
                v4[0] += bs; v4[1] += bs; v4[2] += bs; v4[3] += bs;
                *(f32x4*)&OTv[16 * (2 * th + tcl) + l16][16 * nq + 4 * quad] = v4;
            }
            __syncthreads();
            int cl = t >> 2, np = (t & 3) * 8;
            int ch = (ot - 2) * 64 + cl;
            f32x4 o0 = *(const f32x4*)&OTv[cl][np];
            f32x4 o1 = *(const f32x4*)&OTv[cl][np + 4];
            union { __bf16 h[8]; uint4 u; } pk;
            #pragma unroll
            for (int u2 = 0; u2 < 4; u2++) {
                pk.h[u2]     = (__bf16)o0[u2];
                pk.h[u2 + 4] = (__bf16)o1[u2];
            }
            *(uint4*)&vo[((size_t)b * CDIM + ch) * NPTS + n0 + np] = pk.u;
        }
    }
}

// ---------------------------------------------------------------------------
// MFMA flash attention, round 18: 8-wave single block per CU.
// grid (NPTS/128, CDIM/128, B) = 256 blocks (1/CU), block 512 (8 waves:
// r = w>>1 in 0..3 = 32-row slice of the 128-i tile, jh = w&1).
// Rationale: the two formerly co-resident 4-wave blocks staged IDENTICAL
// K tiles and V c-slices; merging halves DMA-LDS-write traffic (750->375
// cyc/CU-iter on the measured binding pipe, 72%->58% busy) and halves
// K/V FETCH from L2. All per-wave read/swizzle/QK/exp/permlane/PV code is
// r14/r17-verbatim (r just spans 0..3); staging chunks redistribute over
// 8 waves; epilogue same algorithm with doubled extents.
// ---------------------------------------------------------------------------
__global__ __launch_bounds__(512, 1) void attn_kernel(
    const __bf16* __restrict__ qT, const __bf16* __restrict__ kT,
    const __bf16* __restrict__ vin, const float* __restrict__ xin,
    const float* __restrict__ gptr, float* __restrict__ out)
{
    __shared__ __align__(16) unsigned char sm[70144];
    unsigned char* Kb = sm;                  // [2][64 rows][128 B] = 16384
    unsigned char* Vb = sm + 16384;          // [2][128 rows][128 B] = 32768
    // epilogue overlays (after barrier): Opart 256 slots x 272B = 69632,
    // Lp [128] f32 at 69632; OTa [128][132] f32 = 67584

    const int t    = threadIdx.x;   // 0..511
    const int w    = t >> 6;        // 0..7
    const int lane = t & 63;
    const int quad = lane >> 4;
    const int l16  = lane & 15;
    const int r    = w >> 1;        // i row slice 0..3
    const int jh   = w & 1;         // j half

    const int b  = blockIdx.z;
    const int i0 = blockIdx.x * 128;
    const int c0 = blockIdx.y * 128;

    const __bf16* qb = qT  + (size_t)b * NPTS * C4DIM;
    const __bf16* kb = kT  + (size_t)b * NPTS * C4DIM;
    const __bf16* vb = vin + (size_t)b * CDIM * NPTS;

    // DMA offsets: K 8KB = 1 chunk/wave; V 16KB = 2 chunks/wave
    const int swz = (lane & 7) ^ ((lane >> 3) & 7);
    int koff, voff[2];
    {
        int row = w * 8 + (lane >> 3);                 // K row 0..63
        koff = row * 128 + swz * 16;
    }
    #pragma unroll
    for (int s = 0; s < 2; s++) {
        int row = (2 * w + s) * 8 + (lane >> 3);       // V row (channel) 0..127
        voff[s] = (c0 + row) * (NPTS * 2) + swz * 16;
    }

    // Q B-frags (swapped QK): lane l16 = i col, k = c = kc*32 + quad*8
    bf16x8 aq[2][2];
    #pragma unroll
    for (int rt = 0; rt < 2; rt++)
        #pragma unroll
        for (int kc = 0; kc < 2; kc++)
            aq[rt][kc] = *(const bf16x8*)&qb[(size_t)(i0 + 32 * r + 16 * rt + l16) * C4DIM
                                             + kc * 32 + quad * 8];

    bf16x8 vone;
    #pragma unroll
    for (int u = 0; u < 8; u++) vone[u] = (__bf16)1.0f;

    f32x4 O[2][8], lacc[2];
    #pragma unroll
    for (int rt = 0; rt < 2; rt++) {
        lacc[rt] = (f32x4)(0.f);
        #pragma unroll
        for (int tc = 0; tc < 8; tc++) O[rt][tc] = (f32x4)(0.f);
    }

    // prologue DMA tile 0 -> buf 0
    {
        const char* kbase = (const char*)kb;
        const char* vbase = (const char*)vb;
        async_cp16(kbase + koff, Kb + w * 1024);
        #pragma unroll
        for (int s = 0; s < 2; s++) async_cp16(vbase + voff[s], Vb + (2 * w + s) * 1024);
    }

    int p = 0;
    for (int j0 = 0; j0 < NPTS; j0 += 64, p ^= 1) {
        __syncthreads();   // drains DMA into buf p; buf p^1 reads done

        if (j0 + 64 < NPTS) {
            const char* kbase = (const char*)kb + (size_t)(j0 + 64) * (C4DIM * 2);
            const char* vbase = (const char*)vb + (size_t)(j0 + 64) * 2;
            unsigned char* Kd = Kb + (p ^ 1) * 8192;
            unsigned char* Vd = Vb + (p ^ 1) * 16384;
            async_cp16(kbase + koff, Kd + w * 1024);
            #pragma unroll
            for (int s = 0; s < 2; s++) async_cp16(vbase + voff[s], Vd + (2 * w + s) * 1024);
        }

        const unsigned char* K = Kb + p * 8192;
        const unsigned char* V = Vb + p * 16384;

        // ---- issue ALL LDS reads up front: 4 K + 8 V b128 (r17 hoist —
        // V latency hides under QK + exp/pack; with 1 block/CU this is the
        // only latency cover available)
        bf16x8 ka[2][2];   // [kc][jt]
        #pragma unroll
        for (int kc = 0; kc < 2; kc++)
            #pragma unroll
            for (int jt = 0; jt < 2; jt++) {
                int row = 32 * jh + 16 * jt + l16;
                int slot = (kc * 4 + quad) ^ (l16 & 7);
                ka[kc][jt] = *(const bf16x8*)(K + row * 128 + slot * 16);
            }
        bf16x8 vv[8];
        #pragma unroll
        for (int tc = 0; tc < 8; tc++) {
            int row = 16 * tc + l16;
            int slot = (jh * 4 + quad) ^ (l16 & 7);
            vv[tc] = *(const bf16x8*)(V + row * 128 + slot * 16);
        }

        // ---- swapped QK: S[jt][it], lane holds S[i=16it+l16][j=16jt+4quad+r4]
        f32x4 S[2][2];
        #pragma unroll
        for (int jt = 0; jt < 2; jt++)
            #pragma unroll
            for (int it = 0; it < 2; it++) S[jt][it] = (f32x4)(0.f);
        #pragma unroll
        for (int kc = 0; kc < 2; kc++)
            #pragma unroll
            for (int jt = 0; jt < 2; jt++)
                #pragma unroll
                for (int it = 0; it < 2; it++)
                    S[jt][it] = __builtin_amdgcn_mfma_f32_16x16x32_bf16(
                        ka[kc][jt], aq[it][kc], S[jt][it], 0, 0, 0);

        // ---- P = exp(s-32); pack + permlane-redistribute into k32 A-frags
        bf16x8 paf[2];
        #pragma unroll
        for (int it = 0; it < 2; it++) {
            float e[2][4];
            #pragma unroll
            for (int jt = 0; jt < 2; jt++)
                #pragma unroll
                for (int r4 = 0; r4 < 4; r4++)
                    e[jt][r4] = __builtin_amdgcn_exp2f(
                        __builtin_fmaf(S[jt][it][r4], 1.44269504088896340736f,
                                       -46.16624130844683f));
            union { unsigned u[4]; bf16x8 v; } fr;
            #pragma unroll
            for (int h = 0; h < 2; h++) {
                unsigned A = cvt_pk_bf16(e[0][2 * h], e[0][2 * h + 1]);  // jt0
                unsigned B = cvt_pk_bf16(e[1][2 * h], e[1][2 * h + 1]);  // jt1
                auto t2 = __builtin_amdgcn_permlane32_swap(A, B, false, false);
                auto xy = __builtin_amdgcn_permlane16_swap(t2[0], t2[1], false, false);
                fr.u[h]     = xy[0];   // k = 8*quad + 2h, +1
                fr.u[2 + h] = xy[1];   // k = 8*quad + 4 + 2h, +1
            }
            paf[it] = fr.v;
        }

        // ---- PV: k32 MFMAs from preloaded vv (pure-register cluster)
        __builtin_amdgcn_s_setprio(1);
        #pragma unroll
        for (int tc = 0; tc < 8; tc++)
            #pragma unroll
            for (int it = 0; it < 2; it++)
                O[it][tc] = __builtin_amdgcn_mfma_f32_16x16x32_bf16(
                    paf[it], vv[tc], O[it][tc], 0, 0, 0);
        #pragma unroll
        for (int it = 0; it < 2; it++)
            lacc[it] = __builtin_amdgcn_mfma_f32_16x16x32_bf16(paf[it], vone,
                                                               lacc[it], 0, 0, 0);
        __builtin_amdgcn_s_setprio(0);
    }

    // ---- epilogue: combine j-half partials, gamma/l scale, transpose, +x
    __syncthreads();   // all K/V reads done; sm reusable
    const float g = gptr[0];
    float* Lp = (float*)(sm + 69632);

    if (jh == 1) {
        float* dst = (float*)(sm + (size_t)(r * 64 + lane) * 272);
        #pragma unroll
        for (int rt = 0; rt < 2; rt++)
            #pragma unroll
            for (int tc = 0; tc < 8; tc++)
                *(f32x4*)(dst + (rt * 8 + tc) * 4) = O[rt][tc];
        if (l16 == 0) {
            #pragma unroll
            for (int rt = 0; rt < 2; rt++)
                #pragma unroll
                for (int r4 = 0; r4 < 4; r4++)
                    Lp[32 * r + 16 * rt + 4 * quad + r4] = lacc[rt][r4];
        }
    }
    __syncthreads();

    float inv[2][4];
    if (jh == 0) {
        const float* src = (const float*)(sm + (size_t)(r * 64 + lane) * 272);
        #pragma unroll
        for (int rt = 0; rt < 2; rt++)
            #pragma unroll
            for (int tc = 0; tc < 8; tc++)
                O[rt][tc] += *(const f32x4*)(src + (rt * 8 + tc) * 4);
        #pragma unroll
        for (int rt = 0; rt < 2; rt++)
            #pragma unroll
            for (int r4 = 0; r4 < 4; r4++) {
                float ls = lacc[rt][r4] + Lp[32 * r + 16 * rt + 4 * quad + r4];
                inv[rt][r4] = g / ls;
            }
    }
    __syncthreads();   // partial reads done; OTa overlays same bytes

    auto OTa = (float (*)[132])sm;           // [128 c][132] fp32 (i-cols 0..127)
    if (jh == 0) {
        #pragma unroll
        for (int rt = 0; rt < 2; rt++)
            #pragma unroll
            for (int tc = 0; tc < 8; tc++) {
                int c = 16 * tc + l16;
                float4 f;
                f.x = O[rt][tc][0] * inv[rt][0];
                f.y = O[rt][tc][1] * inv[rt][1];
                f.z = O[rt][tc][2] * inv[rt][2];
                f.w = O[rt][tc][3] * inv[rt][3];
                *(float4*)&OTa[c][32 * r + 16 * rt + 4 * quad] = f;
            }
    }
    __syncthreads();

    const float* xb = xin + (size_t)b * CDIM * NPTS;
    float*       ob = out + (size_t)b * CDIM * NPTS;
    #pragma unroll
    for (int s = 0; s < 8; s++) {
        int lin = t + 512 * s;            // 0..4095
        int c = lin >> 5, col = (lin & 31) * 4;
        size_t gi = (size_t)(c0 + c) * NPTS + i0 + col;
        float4 ov = *(const float4*)&OTa[c][col];
        float4 xv = *(const float4*)&xb[gi];
        float4 rr;
        rr.x = ov.x + xv.x; rr.y = ov.y + xv.y;
        rr.z = ov.z + xv.z; rr.w = ov.w + xv.w;
        *(float4*)&ob[gi] = rr;
    }
}

extern "C" void kernel_launch(void* const* d_in, const int* in_sizes, int n_in,
                              void* d_out, int out_size, void* d_ws, size_t ws_size,
                              hipStream_t stream) {
    const float* x     = (const float*)d_in[0];
    const float* Wq    = (const float*)d_in[1];
    const float* bq    = (const float*)d_in[2];
    const float* Wk    = (const float*)d_in[3];
    const float* bk    = (const float*)d_in[4];
    const float* Wv    = (const float*)d_in[5];
    const float* bv    = (const float*)d_in[6];
    const float* gamma = (const float*)d_in[7];

    const int B = 4;
    __bf16* qT  = (__bf16*)d_ws;                        // 2 MB
    __bf16* kT  = qT + (size_t)B * NPTS * C4DIM;        // 2 MB
    __bf16* v   = kT + (size_t)B * NPTS * C4DIM;        // 8 MB
    __bf16* wsz = v  + (size_t)B * CDIM * NPTS;         // 192 KB (swizzled bf16 W)

    wprep_kernel<<<96, 256, 0, stream>>>(Wq, Wk, Wv, wsz);

    proj_kernel<<<dim3(NPTS/32, B), 256, 0, stream>>>(
        x, bq, bk, bv, wsz, qT, kT, v);

    attn_kernel<<<dim3(NPTS/128, CDIM/128, B), 512, 0, stream>>>(
        qT, kT, v, x, gamma, (float*)d_out);
}

// Round 13
// 149.050 us; speedup vs baseline: 1.7924x; 1.0058x over previous
//
#include <hip/hip_runtime.h>

#define NPTS 4096
#define CDIM 256
#define C4DIM 64

typedef __bf16 bf16x8 __attribute__((ext_vector_type(8)));
typedef float  f32x4  __attribute__((ext_vector_type(4)));

__device__ __forceinline__ void async_cp16(const void* g, void* l) {
    __builtin_amdgcn_global_load_lds(
        (const __attribute__((address_space(1))) void*)g,
        (__attribute__((address_space(3))) void*)l, 16, 0, 0);
}

// v_cvt_pk_bf16_f32: D.lo16 = bf16(S0), D.hi16 = bf16(S1). No builtin on
// gfx950 (learn_hip m240) -> inline asm.
__device__ __forceinline__ unsigned cvt_pk_bf16(float lo, float hi) {
    unsigned r;
    asm("v_cvt_pk_bf16_f32 %0, %1, %2" : "=v"(r) : "v"(lo), "v"(hi));
    return r;
}

// ---------------------------------------------------------------------------
// W prep: fp32 -> bf16, rows [Wq(64) | Wk(64) | Wv(256)] = 384 x 256,
// with 16B-group swizzle within each 512B row: phys_group = g ^ (row & 7).
// (verbatim, HW-verified)
// ---------------------------------------------------------------------------
__global__ __launch_bounds__(256) void wprep_kernel(
    const float* __restrict__ Wq, const float* __restrict__ Wk,
    const float* __restrict__ Wv, __bf16* __restrict__ wsz)
{
    int idx = blockIdx.x * 256 + threadIdx.x;   // 0..24575
    int row = idx >> 6;                         // 0..383
    int l   = idx & 63;                         // float4 index within row
    const float* src;
    if (row < 64)       src = Wq + (size_t)row * CDIM;
    else if (row < 128) src = Wk + (size_t)(row - 64) * CDIM;
    else                src = Wv + (size_t)(row - 128) * CDIM;
    float4 f = *(const float4*)&src[l * 4];
    int g  = l >> 1;                 // logical 16B group 0..31
    int gp = g ^ (row & 7);          // physical slot
    union { __bf16 h[4]; uint2 u; } pk;
    pk.h[0] = (__bf16)f.x; pk.h[1] = (__bf16)f.y;
    pk.h[2] = (__bf16)f.z; pk.h[3] = (__bf16)f.w;
    *(uint2*)&wsz[(size_t)row * CDIM + gp * 8 + (l & 1) * 4] = pk.u;
}

// ---------------------------------------------------------------------------
// MFMA projection (round-7 version, verified): 32-n tiles,
// grid (NPTS/32, B), block 256; LDS 64KB -> 2 blocks/CU.
// ---------------------------------------------------------------------------
__global__ __launch_bounds__(256, 2) void proj_kernel(
    const float* __restrict__ x,
    const float* __restrict__ bq, const float* __restrict__ bk,
    const float* __restrict__ bv, const __bf16* __restrict__ wsz,
    __bf16* __restrict__ qT, __bf16* __restrict__ kT, __bf16* __restrict__ vo)
{
    __shared__ __align__(16) unsigned char sm[65536];
    auto Xs = (float (*)[33])sm;                 // [256][33] fp32, dies after A-build

    const int t    = threadIdx.x;
    const int w    = t >> 6;
    const int lane = t & 63;
    const int quad = lane >> 4;
    const int l16  = lane & 15;
    const int nq   = w >> 1;
    const int th   = w & 1;

    const int n0 = blockIdx.x * 32;
    const int b  = blockIdx.y;

    #pragma unroll
    for (int s = 0; s < 8; s++) {
        int lin = t + 256 * s;
        int c = lin >> 3, n4 = (lin & 7) * 4;
        *(float4*)&Xs[c][n4] =
            *(const float4*)&x[((size_t)b * CDIM + c) * NPTS + n0 + n4];
    }
    __syncthreads();

    bf16x8 af[8];
    #pragma unroll
    for (int kc = 0; kc < 8; kc++) {
        union { __bf16 h8[8]; bf16x8 v; } pk;
        #pragma unroll
        for (int u = 0; u < 8; u++)
            pk.h8[u] = (__bf16)Xs[kc * 32 + quad * 8 + u][16 * nq + l16];
        af[kc] = pk.v;
    }
    __syncthreads();

    const int lhalf = lane >> 5;
    const int rlow  = (2 * w + lhalf) & 7;
    const int slane = ((lane & 31) ^ rlow) * 8;

    #pragma unroll
    for (int s = 0; s < 8; s++)
        async_cp16(wsz + (size_t)(8 * s + 2 * w + lhalf) * CDIM + slane,
                   sm + (s * 4 + w) * 1024);

    f32x4 acc[6][2];
    #pragma unroll
    for (int ot = 0; ot < 6; ot++) {
        acc[ot][0] = (f32x4)(0.f);
        acc[ot][1] = (f32x4)(0.f);
    }

    #pragma unroll
    for (int ot = 0; ot < 6; ot++) {
        __syncthreads();
        if (ot < 5) {
            #pragma unroll
            for (int s = 0; s < 8; s++)
                async_cp16(wsz + (size_t)((ot + 1) * 64 + 8 * s + 2 * w + lhalf) * CDIM + slane,
                           sm + ((ot + 1) & 1) * 32768 + (s * 4 + w) * 1024);
        }
        const unsigned char* Wp = sm + (ot & 1) * 32768;
        #pragma unroll
        for (int kc = 0; kc < 8; kc++) {
            bf16x8 bw[2];
            #pragma unroll
            for (int tcl = 0; tcl < 2; tcl++)
                bw[tcl] = *(const bf16x8*)(Wp + (16 * (2 * th + tcl) + l16) * 512
                                              + (((kc * 4 + quad) ^ (l16 & 7)) << 4));
            #pragma unroll
            for (int tcl = 0; tcl < 2; tcl++)
                acc[ot][tcl] = __builtin_amdgcn_mfma_f32_16x16x32_bf16(
                    af[kc], bw[tcl], acc[ot][tcl], 0, 0, 0);
        }
    }

    {
        auto OT = (float (*)[68])sm;
        #pragma unroll
        for (int ot = 0; ot < 2; ot++) {
            __syncthreads();
            const float* bias = ot ? bk : bq;
            #pragma unroll
            for (int tcl = 0; tcl < 2; tcl++) {
                float bs = bias[16 * (2 * th + tcl) + l16];
                #pragma unroll
                for (int r4 = 0; r4 < 4; r4++)
                    OT[16 * nq + 4 * quad + r4][16 * (2 * th + tcl) + l16] =
                        acc[ot][tcl][r4] + bs;
            }
            __syncthreads();
            __bf16* outp = (ot == 0 ? qT : kT) + (size_t)b * NPTS * C4DIM;
            int n = t >> 3, op = (t & 7) * 8;
            f32x4 o0 = *(const f32x4*)&OT[n][op];
            f32x4 o1 = *(const f32x4*)&OT[n][op + 4];
            union { __bf16 h[8]; uint4 u; } pk;
            #pragma unroll
            for (int u2 = 0; u2 < 4; u2++) {
                pk.h[u2]     = (__bf16)o0[u2];
                pk.h[u2 + 4] = (__bf16)o1[u2];
            }
            *(uint4*)&outp[(size_t)(n0 + n) * C4DIM + op] = pk.u;
        }
    }
    {
        auto OTv = (float (*)[36])sm;
        #pragma unroll
        for (int ot = 2; ot < 6; ot++) {
            __syncthreads();
            #pragma unroll
            for (int tcl = 0; tcl < 2; tcl++) {
                float bs = bv[(ot - 2) * 64 + 16 * (2 * th + tcl) + l16];
                f32x4 v4 = acc[ot][tcl];
                v4[0] += bs; v4[1] += bs; v4[2] += bs; v4[3] += bs;
                *(f32x4*)&OTv[16 * (2 * th + tcl) + l16][16 * nq + 4 * quad] = v4;
            }
            __syncthreads();
            int cl = t >> 2, np = (t & 3) * 8;
            int ch = (ot - 2) * 64 + cl;
            f32x4 o0 = *(const f32x4*)&OTv[cl][np];
            f32x4 o1 = *(const f32x4*)&OTv[cl][np + 4];
            union { __bf16 h[8]; uint4 u; } pk;
            #pragma unroll
            for (int u2 = 0; u2 < 4; u2++) {
                pk.h[u2]     = (__bf16)o0[u2];
                pk.h[u2 + 4] = (__bf16)o1[u2];
            }
            *(uint4*)&vo[((size_t)b * CDIM + ch) * NPTS + n0 + np] = pk.u;
        }
    }
}

// ---------------------------------------------------------------------------
// MFMA flash attention, round 19 = r18 structure (8-wave single block/CU,
// verified correct; conflicts = 0) with j-tile 64 -> 128: each double-buffer
// period stages TWO K sub-tiles (8KB) + TWO V sub-tiles (16KB) laid out
// bit-identically to r18's tiles; the inner js=0,1 loop runs the verbatim
// r18 body with shifted bases. Barrier + vmcnt(0)-drain count halves
// (64 -> 32) -- attacks the ~1300 cyc/iter of unaccounted per-barrier
// overhead (measured: 2690 cyc/iter vs 1344 LDS + ~240 VALU + 175 MFMA).
// The two js slices are independent -> extra ILP across slices.
// LDS 96KB, 1 block/CU (unchanged).
// ---------------------------------------------------------------------------
__global__ __launch_bounds__(512, 1) void attn_kernel(
    const __bf16* __restrict__ qT, const __bf16* __restrict__ kT,
    const __bf16* __restrict__ vin, const float* __restrict__ xin,
    const float* __restrict__ gptr, float* __restrict__ out)
{
    __shared__ __align__(16) unsigned char sm[98304];
    unsigned char* Kb = sm;                  // [2 buf][2 js][64 rows][128 B] = 32768
    unsigned char* Vb = sm + 32768;          // [2 buf][2 js][128 rows][128 B] = 65536
    // epilogue overlays (after barrier): Opart 256 slots x 272B = 69632,
    // Lp [128] f32 at 69632; OTa [128][132] f32 = 67584

    const int t    = threadIdx.x;   // 0..511
    const int w    = t >> 6;        // 0..7
    const int lane = t & 63;
    const int quad = lane >> 4;
    const int l16  = lane & 15;
    const int r    = w >> 1;        // i row slice 0..3
    const int jh   = w & 1;         // j half (within a 64-j sub-tile)

    const int b  = blockIdx.z;
    const int i0 = blockIdx.x * 128;
    const int c0 = blockIdx.y * 128;

    const __bf16* qb = qT  + (size_t)b * NPTS * C4DIM;
    const __bf16* kb = kT  + (size_t)b * NPTS * C4DIM;
    const __bf16* vb = vin + (size_t)b * CDIM * NPTS;

    // DMA offsets (identical to r18; applied per js sub-tile)
    const int swz = (lane & 7) ^ ((lane >> 3) & 7);
    int koff, voff[2];
    {
        int row = w * 8 + (lane >> 3);                 // K row 0..63
        koff = row * 128 + swz * 16;
    }
    #pragma unroll
    for (int s = 0; s < 2; s++) {
        int row = (2 * w + s) * 8 + (lane >> 3);       // V row (channel) 0..127
        voff[s] = (c0 + row) * (NPTS * 2) + swz * 16;
    }

    // Q B-frags (swapped QK): lane l16 = i col, k = c = kc*32 + quad*8
    bf16x8 aq[2][2];
    #pragma unroll
    for (int rt = 0; rt < 2; rt++)
        #pragma unroll
        for (int kc = 0; kc < 2; kc++)
            aq[rt][kc] = *(const bf16x8*)&qb[(size_t)(i0 + 32 * r + 16 * rt + l16) * C4DIM
                                             + kc * 32 + quad * 8];

    bf16x8 vone;
    #pragma unroll
    for (int u = 0; u < 8; u++) vone[u] = (__bf16)1.0f;

    f32x4 O[2][8], lacc[2];
    #pragma unroll
    for (int rt = 0; rt < 2; rt++) {
        lacc[rt] = (f32x4)(0.f);
        #pragma unroll
        for (int tc = 0; tc < 8; tc++) O[rt][tc] = (f32x4)(0.f);
    }

    // stage one 128-j tile (two r18-layout sub-tiles) into buf (Kd,Vd)
    auto issue_tile = [&](int j, unsigned char* Kd, unsigned char* Vd) {
        #pragma unroll
        for (int js = 0; js < 2; js++) {
            const char* kbase = (const char*)kb + (size_t)(j + 64 * js) * (C4DIM * 2);
            const char* vbase = (const char*)vb + (size_t)(j + 64 * js) * 2;
            async_cp16(kbase + koff, Kd + js * 8192 + w * 1024);
            #pragma unroll
            for (int s = 0; s < 2; s++)
                async_cp16(vbase + voff[s], Vd + js * 16384 + (2 * w + s) * 1024);
        }
    };

    // prologue DMA tile 0 -> buf 0
    issue_tile(0, Kb, Vb);

    int p = 0;
    for (int j0 = 0; j0 < NPTS; j0 += 128, p ^= 1) {
        __syncthreads();   // drains DMA into buf p; buf p^1 reads done

        if (j0 + 128 < NPTS)
            issue_tile(j0 + 128, Kb + (p ^ 1) * 16384, Vb + (p ^ 1) * 32768);

        #pragma unroll
        for (int js = 0; js < 2; js++) {
            const unsigned char* K = Kb + p * 16384 + js * 8192;
            const unsigned char* V = Vb + p * 32768 + js * 16384;

            // ---- all LDS reads up front: 4 K + 8 V b128 (r17 hoist)
            bf16x8 ka[2][2];   // [kc][jt]
            #pragma unroll
            for (int kc = 0; kc < 2; kc++)
                #pragma unroll
                for (int jt = 0; jt < 2; jt++) {
                    int row = 32 * jh + 16 * jt + l16;
                    int slot = (kc * 4 + quad) ^ (l16 & 7);
                    ka[kc][jt] = *(const bf16x8*)(K + row * 128 + slot * 16);
                }
            bf16x8 vv[8];
            #pragma unroll
            for (int tc = 0; tc < 8; tc++) {
                int row = 16 * tc + l16;
                int slot = (jh * 4 + quad) ^ (l16 & 7);
                vv[tc] = *(const bf16x8*)(V + row * 128 + slot * 16);
            }

            // ---- swapped QK: S[jt][it] = S[i=16it+l16][j=16jt+4quad+r4]
            f32x4 S[2][2];
            #pragma unroll
            for (int jt = 0; jt < 2; jt++)
                #pragma unroll
                for (int it = 0; it < 2; it++) S[jt][it] = (f32x4)(0.f);
            #pragma unroll
            for (int kc = 0; kc < 2; kc++)
                #pragma unroll
                for (int jt = 0; jt < 2; jt++)
                    #pragma unroll
                    for (int it = 0; it < 2; it++)
                        S[jt][it] = __builtin_amdgcn_mfma_f32_16x16x32_bf16(
                            ka[kc][jt], aq[it][kc], S[jt][it], 0, 0, 0);

            // ---- P = exp(s-32); pack + permlane-redistribute to k32 A-frags
            bf16x8 paf[2];
            #pragma unroll
            for (int it = 0; it < 2; it++) {
                float e[2][4];
                #pragma unroll
                for (int jt = 0; jt < 2; jt++)
                    #pragma unroll
                    for (int r4 = 0; r4 < 4; r4++)
                        e[jt][r4] = __builtin_amdgcn_exp2f(
                            __builtin_fmaf(S[jt][it][r4], 1.44269504088896340736f,
                                           -46.16624130844683f));
                union { unsigned u[4]; bf16x8 v; } fr;
                #pragma unroll
                for (int h = 0; h < 2; h++) {
                    unsigned A = cvt_pk_bf16(e[0][2 * h], e[0][2 * h + 1]);  // jt0
                    unsigned B = cvt_pk_bf16(e[1][2 * h], e[1][2 * h + 1]);  // jt1
                    auto t2 = __builtin_amdgcn_permlane32_swap(A, B, false, false);
                    auto xy = __builtin_amdgcn_permlane16_swap(t2[0], t2[1], false, false);
                    fr.u[h]     = xy[0];   // k = 8*quad + 2h, +1
                    fr.u[2 + h] = xy[1];   // k = 8*quad + 4 + 2h, +1
                }
                paf[it] = fr.v;
            }

            // ---- PV: k32 MFMAs from preloaded vv (pure-register cluster)
            __builtin_amdgcn_s_setprio(1);
            #pragma unroll
            for (int tc = 0; tc < 8; tc++)
                #pragma unroll
                for (int it = 0; it < 2; it++)
                    O[it][tc] = __builtin_amdgcn_mfma_f32_16x16x32_bf16(
                        paf[it], vv[tc], O[it][tc], 0, 0, 0);
            #pragma unroll
            for (int it = 0; it < 2; it++)
                lacc[it] = __builtin_amdgcn_mfma_f32_16x16x32_bf16(paf[it], vone,
                                                                   lacc[it], 0, 0, 0);
            __builtin_amdgcn_s_setprio(0);
        }
    }

    // ---- epilogue: combine j-half partials, gamma/l scale, transpose, +x
    __syncthreads();   // all K/V reads done; sm reusable
    const float g = gptr[0];
    float* Lp = (float*)(sm + 69632);

    if (jh == 1) {
        float* dst = (float*)(sm + (size_t)(r * 64 + lane) * 272);
        #pragma unroll
        for (int rt = 0; rt < 2; rt++)
            #pragma unroll
            for (int tc = 0; tc < 8; tc++)
                *(f32x4*)(dst + (rt * 8 + tc) * 4) = O[rt][tc];
        if (l16 == 0) {
            #pragma unroll
            for (int rt = 0; rt < 2; rt++)
                #pragma unroll
                for (int r4 = 0; r4 < 4; r4++)
                    Lp[32 * r + 16 * rt + 4 * quad + r4] = lacc[rt][r4];
        }
    }
    __syncthreads();

    float inv[2][4];
    if (jh == 0) {
        const float* src = (const float*)(sm + (size_t)(r * 64 + lane) * 272);
        #pragma unroll
        for (int rt = 0; rt < 2; rt++)
            #pragma unroll
            for (int tc = 0; tc < 8; tc++)
                O[rt][tc] += *(const f32x4*)(src + (rt * 8 + tc) * 4);
        #pragma unroll
        for (int rt = 0; rt < 2; rt++)
            #pragma unroll
            for (int r4 = 0; r4 < 4; r4++) {
                float ls = lacc[rt][r4] + Lp[32 * r + 16 * rt + 4 * quad + r4];
                inv[rt][r4] = g / ls;
            }
    }
    __syncthreads();   // partial reads done; OTa overlays same bytes

    auto OTa = (float (*)[132])sm;           // [128 c][132] fp32 (i-cols 0..127)
    if (jh == 0) {
        #pragma unroll
        for (int rt = 0; rt < 2; rt++)
            #pragma unroll
            for (int tc = 0; tc < 8; tc++) {
                int c = 16 * tc + l16;
                float4 f;
                f.x = O[rt][tc][0] * inv[rt][0];
                f.y = O[rt][tc][1] * inv[rt][1];
                f.z = O[rt][tc][2] * inv[rt][2];
                f.w = O[rt][tc][3] * inv[rt][3];
                *(float4*)&OTa[c][32 * r + 16 * rt + 4 * quad] = f;
            }
    }
    __syncthreads();

    const float* xb = xin + (size_t)b * CDIM * NPTS;
    float*       ob = out + (size_t)b * CDIM * NPTS;
    #pragma unroll
    for (int s = 0; s < 8; s++) {
        int lin = t + 512 * s;            // 0..4095
        int c = lin >> 5, col = (lin & 31) * 4;
        size_t gi = (size_t)(c0 + c) * NPTS + i0 + col;
        float4 ov = *(const float4*)&OTa[c][col];
        float4 xv = *(const float4*)&xb[gi];
        float4 rr;
        rr.x = ov.x + xv.x; rr.y = ov.y + xv.y;
        rr.z = ov.z + xv.z; rr.w = ov.w + xv.w;
        *(float4*)&ob[gi] = rr;
    }
}

extern "C" void kernel_launch(void* const* d_in, const int* in_sizes, int n_in,
                              void* d_out, int out_size, void* d_ws, size_t ws_size,
                              hipStream_t stream) {
    const float* x     = (const float*)d_in[0];
    const float* Wq    = (const float*)d_in[1];
    const float* bq    = (const float*)d_in[2];
    const float* Wk    = (const float*)d_in[3];
    const float* bk    = (const float*)d_in[4];
    const float* Wv    = (const float*)d_in[5];
    const float* bv    = (const float*)d_in[6];
    const float* gamma = (const float*)d_in[7];

    const int B = 4;
    __bf16* qT  = (__bf16*)d_ws;                        // 2 MB
    __bf16* kT  = qT + (size_t)B * NPTS * C4DIM;        // 2 MB
    __bf16* v   = kT + (size_t)B * NPTS * C4DIM;        // 8 MB
    __bf16* wsz = v  + (size_t)B * CDIM * NPTS;         // 192 KB (swizzled bf16 W)

    wprep_kernel<<<96, 256, 0, stream>>>(Wq, Wk, Wv, wsz);

    proj_kernel<<<dim3(NPTS/32, B), 256, 0, stream>>>(
        x, bq, bk, bv, wsz, qT, kT, v);

    attn_kernel<<<dim3(NPTS/128, CDIM/128, B), 512, 0, stream>>>(
        qT, kT, v, x, gamma, (float*)d_out);
}